// Round 1
// baseline (604.084 us; speedup 1.0000x reference)
//
#include <hip/hip_runtime.h>
#include <stdint.h>

typedef __attribute__((ext_vector_type(8))) short short8;
typedef __attribute__((ext_vector_type(4))) float f32x4;

#define B_ 4
#define T_ 2048
#define C_ 1024
#define H_ 16
#define D_ 64
#define C3_ 3072

__device__ __forceinline__ unsigned short f2bf(float f) {
    union { float f; uint32_t u; } v; v.f = f;
    uint32_t r = v.u + 0x7FFFu + ((v.u >> 16) & 1u);
    return (unsigned short)(r >> 16);
}

// ---------------- fp32 -> bf16 elementwise ----------------
__global__ void k_cvt_bf16(const float* __restrict__ in, unsigned short* __restrict__ out, int n4) {
    int i = blockIdx.x * blockDim.x + threadIdx.x;
    if (i >= n4) return;
    float4 v = ((const float4*)in)[i];
    unsigned short o0 = f2bf(v.x), o1 = f2bf(v.y), o2 = f2bf(v.z), o3 = f2bf(v.w);
    unsigned long long packed = (unsigned long long)o0 | ((unsigned long long)o1 << 16)
        | ((unsigned long long)o2 << 32) | ((unsigned long long)o3 << 48);
    *(unsigned long long*)(out + (size_t)i * 4) = packed;
}

// ---------------- W[K][N] fp32 -> WT[N][K] bf16 ----------------
__global__ void k_wtrans(const float* __restrict__ W, unsigned short* __restrict__ WT, int K, int N) {
    __shared__ float t[32][33];
    int n0 = blockIdx.x * 32, k0 = blockIdx.y * 32;
    int tx = threadIdx.x, ty = threadIdx.y; // (32,8)
#pragma unroll
    for (int i = 0; i < 4; ++i)
        t[ty + i * 8][tx] = W[(size_t)(k0 + ty + i * 8) * N + n0 + tx];
    __syncthreads();
#pragma unroll
    for (int i = 0; i < 4; ++i)
        WT[(size_t)(n0 + ty + i * 8) * K + k0 + tx] = f2bf(t[tx][ty + i * 8]);
}

// ---------------- extract V head-major transposed: vt[bh][d][t] ----------------
__global__ void k_prep_vt(const unsigned short* __restrict__ qkv, unsigned short* __restrict__ vt) {
    int bh = blockIdx.y; int b = bh >> 4, h = bh & 15;
    int t0 = blockIdx.x * 64;
    __shared__ unsigned short tile[64][72];
    int tid = threadIdx.x;
    int r = tid >> 3;          // 0..31
    int c = (tid & 7) * 8;     // 0..56
#pragma unroll
    for (int rr = 0; rr < 64; rr += 32) {
        const unsigned short* src = qkv + (size_t)(b * T_ + t0 + r + rr) * C3_ + 2 * C_ + h * D_ + c;
        short8 v = *(const short8*)src;
#pragma unroll
        for (int j = 0; j < 8; ++j) tile[r + rr][c + j] = (unsigned short)v[j];
    }
    __syncthreads();
#pragma unroll
    for (int rr = 0; rr < 64; rr += 32) {
        int d = r + rr;
        short8 sv;
#pragma unroll
        for (int j = 0; j < 8; ++j) sv[j] = (short)tile[c + j][d];
        *(short8*)(vt + (size_t)bh * D_ * T_ + (size_t)d * T_ + t0 + c) = sv;
    }
}

// ---------------- GEMM: C[M][N] = A[M][K](bf16) @ BT[N][K](bf16)^T + bias ----------------
template<bool OUT_BF16>
__global__ __launch_bounds__(256) void k_gemm_bt(const unsigned short* __restrict__ A,
                                                 const unsigned short* __restrict__ BT,
                                                 const float* __restrict__ bias,
                                                 unsigned short* __restrict__ outb,
                                                 float* __restrict__ outf,
                                                 int M, int N, int K) {
    __shared__ unsigned short a_lds[2][128 * 32];
    __shared__ unsigned short b_lds[2][128 * 32];
    int tid = threadIdx.x;
    int w = tid >> 6, lane = tid & 63;
    int wr = w >> 1, wc = w & 1;
    int m0 = blockIdx.y * 128, n0 = blockIdx.x * 128;
    int lr = lane & 15, lg = lane >> 4;

    f32x4 acc[4][4] = {};

#define STAGE(buf, kt)                                                                              \
    {                                                                                               \
        _Pragma("unroll")                                                                           \
        for (int i = 0; i < 2; ++i) {                                                               \
            int g = i * 256 + tid;                                                                  \
            int row = g >> 2, kc = g & 3;                                                           \
            const unsigned short* srcA = A + (size_t)(m0 + row) * K + (kt) * 32 + kc * 8;           \
            const unsigned short* srcB = BT + (size_t)(n0 + row) * K + (kt) * 32 + kc * 8;          \
            unsigned short* dA = &a_lds[buf][(i * 256 + w * 64) * 8];                               \
            unsigned short* dB = &b_lds[buf][(i * 256 + w * 64) * 8];                               \
            __builtin_amdgcn_global_load_lds((const __attribute__((address_space(1))) void*)srcA,  \
                                             (__attribute__((address_space(3))) void*)dA, 16, 0, 0);\
            __builtin_amdgcn_global_load_lds((const __attribute__((address_space(1))) void*)srcB,  \
                                             (__attribute__((address_space(3))) void*)dB, 16, 0, 0);\
        }                                                                                           \
    }

    int NT = K >> 5;
    STAGE(0, 0);
    asm volatile("s_waitcnt vmcnt(0)" ::: "memory");
    __syncthreads();
    int cur = 0;
    for (int kt = 0; kt < NT; ++kt) {
        if (kt + 1 < NT) STAGE(cur ^ 1, kt + 1);
        int koff = lg * 8;
        short8 a[4], b[4];
#pragma unroll
        for (int i = 0; i < 4; ++i)
            a[i] = *(const short8*)&a_lds[cur][(wr * 64 + i * 16 + lr) * 32 + koff];
#pragma unroll
        for (int j = 0; j < 4; ++j)
            b[j] = *(const short8*)&b_lds[cur][(wc * 64 + j * 16 + lr) * 32 + koff];
#pragma unroll
        for (int i = 0; i < 4; ++i)
#pragma unroll
            for (int j = 0; j < 4; ++j)
                acc[i][j] = __builtin_amdgcn_mfma_f32_16x16x32_bf16(a[i], b[j], acc[i][j], 0, 0, 0);
        asm volatile("s_waitcnt vmcnt(0)" ::: "memory");
        __syncthreads();
        cur ^= 1;
    }
#undef STAGE

#pragma unroll
    for (int i = 0; i < 4; ++i) {
        int row = m0 + wr * 64 + i * 16 + lg * 4;
#pragma unroll
        for (int j = 0; j < 4; ++j) {
            int col = n0 + wc * 64 + j * 16 + lr;
            float bv = bias[col];
#pragma unroll
            for (int r = 0; r < 4; ++r) {
                float v = acc[i][j][r] + bv;
                if (OUT_BF16) outb[(size_t)(row + r) * N + col] = f2bf(v);
                else          outf[(size_t)(row + r) * N + col] = v;
            }
        }
    }
}

// ---------------- causal flash attention ----------------
__global__ __launch_bounds__(256) void k_attn(const unsigned short* __restrict__ qkv,
                                              const unsigned short* __restrict__ vt,
                                              unsigned short* __restrict__ y) {
    int w = threadIdx.x >> 6, lane = threadIdx.x & 63;
    int bh = blockIdx.y; int b = bh >> 4, h = bh & 15;
    int q0 = blockIdx.x * 64;
    int lr = lane & 15, lg = lane >> 4;

    __shared__ unsigned short p_lds[4][16][64];

    const unsigned short* qrow = qkv + (size_t)(b * T_ + q0 + w * 16 + lr) * C3_ + h * D_;
    short8 qf0 = *(const short8*)(qrow + lg * 8);
    short8 qf1 = *(const short8*)(qrow + 32 + lg * 8);

    f32x4 o[4] = {};
    float mreg[4] = {-1e30f, -1e30f, -1e30f, -1e30f};
    float ls[4] = {};

    const unsigned short* kbase = qkv + (size_t)(b * T_) * C3_ + C_ + h * D_;
    const unsigned short* vtb = vt + (size_t)bh * D_ * T_;

    int qg[4];
#pragma unroll
    for (int r = 0; r < 4; ++r) qg[r] = q0 + w * 16 + lg * 4 + r;

    int ntiles = blockIdx.x + 1;
    for (int kt = 0; kt < ntiles; ++kt) {
        int kv0 = kt * 64;
        f32x4 s[4] = {};
#pragma unroll
        for (int j = 0; j < 4; ++j) {
            const unsigned short* krow = kbase + (size_t)(kv0 + j * 16 + lr) * C3_;
            short8 kf0 = *(const short8*)(krow + lg * 8);
            short8 kf1 = *(const short8*)(krow + 32 + lg * 8);
            s[j] = __builtin_amdgcn_mfma_f32_16x16x32_bf16(qf0, kf0, s[j], 0, 0, 0);
            s[j] = __builtin_amdgcn_mfma_f32_16x16x32_bf16(qf1, kf1, s[j], 0, 0, 0);
        }
        float p[4][4];
        float rmax[4] = {-INFINITY, -INFINITY, -INFINITY, -INFINITY};
#pragma unroll
        for (int j = 0; j < 4; ++j) {
            int col = kv0 + j * 16 + lr;
#pragma unroll
            for (int r = 0; r < 4; ++r) {
                float sv = (col <= qg[r]) ? s[j][r] * 0.125f : -INFINITY;
                p[j][r] = sv;
                rmax[r] = fmaxf(rmax[r], sv);
            }
        }
#pragma unroll
        for (int r = 0; r < 4; ++r) {
#pragma unroll
            for (int mk = 1; mk < 16; mk <<= 1)
                rmax[r] = fmaxf(rmax[r], __shfl_xor(rmax[r], mk));
            float mnew = fmaxf(mreg[r], rmax[r]);
            float sc = __expf(mreg[r] - mnew);
            mreg[r] = mnew;
            float rsum = 0.f;
#pragma unroll
            for (int j = 0; j < 4; ++j) {
                float pv = __expf(p[j][r] - mnew);
                p[j][r] = pv;
                rsum += pv;
            }
#pragma unroll
            for (int mk = 1; mk < 16; mk <<= 1)
                rsum += __shfl_xor(rsum, mk);
            ls[r] = ls[r] * sc + rsum;
#pragma unroll
            for (int dt = 0; dt < 4; ++dt) o[dt][r] *= sc;
        }
#pragma unroll
        for (int j = 0; j < 4; ++j)
#pragma unroll
            for (int r = 0; r < 4; ++r)
                p_lds[w][lg * 4 + r][j * 16 + lr] = f2bf(p[j][r]);
        __syncthreads();
        short8 pa0 = *(const short8*)&p_lds[w][lr][lg * 8];
        short8 pa1 = *(const short8*)&p_lds[w][lr][32 + lg * 8];
#pragma unroll
        for (int dt = 0; dt < 4; ++dt) {
            const unsigned short* vrow = vtb + (size_t)(dt * 16 + lr) * T_ + kv0;
            short8 vf0 = *(const short8*)(vrow + lg * 8);
            short8 vf1 = *(const short8*)(vrow + 32 + lg * 8);
            o[dt] = __builtin_amdgcn_mfma_f32_16x16x32_bf16(pa0, vf0, o[dt], 0, 0, 0);
            o[dt] = __builtin_amdgcn_mfma_f32_16x16x32_bf16(pa1, vf1, o[dt], 0, 0, 0);
        }
        __syncthreads();
    }

#pragma unroll
    for (int r = 0; r < 4; ++r) {
        float inv = 1.0f / ls[r];
        int q = q0 + w * 16 + lg * 4 + r;
        unsigned short* yrow = y + (size_t)(b * T_ + q) * C_ + h * D_;
#pragma unroll
        for (int dt = 0; dt < 4; ++dt)
            yrow[dt * 16 + lr] = f2bf(o[dt][r] * inv);
    }
}

extern "C" void kernel_launch(void* const* d_in, const int* in_sizes, int n_in,
                              void* d_out, int out_size, void* d_ws, size_t ws_size,
                              hipStream_t stream) {
    const float* x  = (const float*)d_in[0];
    const float* Wa = (const float*)d_in[1];
    const float* ba = (const float*)d_in[2];
    const float* Wp = (const float*)d_in[3];
    const float* bp = (const float*)d_in[4];
    float* out = (float*)d_out;

    char* ws = (char*)d_ws;
    unsigned short* xb  = (unsigned short*)(ws);                       // 16 MB
    unsigned short* wat = (unsigned short*)(ws + 16777216);            // 6 MB
    unsigned short* wpt = (unsigned short*)(ws + 23068672);            // 2 MB
    unsigned short* qkv = (unsigned short*)(ws + 25165824);            // 48 MB
    unsigned short* vt  = (unsigned short*)(ws + 75497472);            // 16 MB
    unsigned short* y   = xb;  // xb dead after GEMM1; reuse for attention output

    // x -> bf16
    k_cvt_bf16<<<8192, 256, 0, stream>>>(x, xb, (B_ * T_ * C_) / 4);
    // weights -> bf16 transposed
    k_wtrans<<<dim3(C3_ / 32, C_ / 32), dim3(32, 8), 0, stream>>>(Wa, wat, C_, C3_);
    k_wtrans<<<dim3(C_ / 32, C_ / 32), dim3(32, 8), 0, stream>>>(Wp, wpt, C_, C_);
    // qkv = x @ W_attn + b_attn   (bf16 out)
    k_gemm_bt<true><<<dim3(C3_ / 128, (B_ * T_) / 128), 256, 0, stream>>>(
        xb, wat, ba, qkv, nullptr, B_ * T_, C3_, C_);
    // v -> vt[bh][d][t]
    k_prep_vt<<<dim3(T_ / 64, B_ * H_), 256, 0, stream>>>(qkv, vt);
    // attention
    k_attn<<<dim3(T_ / 64, B_ * H_), 256, 0, stream>>>(qkv, vt, y);
    // out = y @ W_proj + b_proj   (fp32 out)
    k_gemm_bt<false><<<dim3(C_ / 128, (B_ * T_) / 128), 256, 0, stream>>>(
        y, wpt, bp, nullptr, out, B_ * T_, C_, C_);
}

// Round 2
// 244.799 us; speedup vs baseline: 2.4677x; 2.4677x over previous
//
#include <hip/hip_runtime.h>
#include <stdint.h>

typedef __attribute__((ext_vector_type(8))) short short8;
typedef __attribute__((ext_vector_type(4))) float f32x4;

#define B_ 4
#define T_ 2048
#define C_ 1024
#define H_ 16
#define D_ 64
#define C3_ 3072

__device__ __forceinline__ unsigned short f2bf(float f) {
    union { float f; uint32_t u; } v; v.f = f;
    uint32_t r = v.u + 0x7FFFu + ((v.u >> 16) & 1u);
    return (unsigned short)(r >> 16);
}

// ---------------- fp32 -> bf16 elementwise ----------------
__global__ void k_cvt_bf16(const float* __restrict__ in, unsigned short* __restrict__ out, int n4) {
    int i = blockIdx.x * blockDim.x + threadIdx.x;
    if (i >= n4) return;
    float4 v = ((const float4*)in)[i];
    unsigned short o0 = f2bf(v.x), o1 = f2bf(v.y), o2 = f2bf(v.z), o3 = f2bf(v.w);
    unsigned long long packed = (unsigned long long)o0 | ((unsigned long long)o1 << 16)
        | ((unsigned long long)o2 << 32) | ((unsigned long long)o3 << 48);
    *(unsigned long long*)(out + (size_t)i * 4) = packed;
}

// ---------------- W[K][N] fp32 -> WT[N][K] bf16 ----------------
__global__ void k_wtrans(const float* __restrict__ W, unsigned short* __restrict__ WT, int K, int N) {
    __shared__ float t[32][33];
    int n0 = blockIdx.x * 32, k0 = blockIdx.y * 32;
    int tx = threadIdx.x, ty = threadIdx.y; // (32,8)
#pragma unroll
    for (int i = 0; i < 4; ++i)
        t[ty + i * 8][tx] = W[(size_t)(k0 + ty + i * 8) * N + n0 + tx];
    __syncthreads();
#pragma unroll
    for (int i = 0; i < 4; ++i)
        WT[(size_t)(n0 + ty + i * 8) * K + k0 + tx] = f2bf(t[tx][ty + i * 8]);
}

// ---------------- extract V head-major transposed: vt[bh][d][t] ----------------
__global__ void k_prep_vt(const unsigned short* __restrict__ qkv, unsigned short* __restrict__ vt) {
    int bh = blockIdx.y; int b = bh >> 4, h = bh & 15;
    int t0 = blockIdx.x * 64;
    __shared__ unsigned short tile[64][72];
    int tid = threadIdx.x;
    int r = tid >> 3;          // 0..31
    int c = (tid & 7) * 8;     // 0..56
#pragma unroll
    for (int rr = 0; rr < 64; rr += 32) {
        const unsigned short* src = qkv + (size_t)(b * T_ + t0 + r + rr) * C3_ + 2 * C_ + h * D_ + c;
        short8 v = *(const short8*)src;
#pragma unroll
        for (int j = 0; j < 8; ++j) tile[r + rr][c + j] = (unsigned short)v[j];
    }
    __syncthreads();
#pragma unroll
    for (int rr = 0; rr < 64; rr += 32) {
        int d = r + rr;
        short8 sv;
#pragma unroll
        for (int j = 0; j < 8; ++j) sv[j] = (short)tile[c + j][d];
        *(short8*)(vt + (size_t)bh * D_ * T_ + (size_t)d * T_ + t0 + c) = sv;
    }
}

// ---------------- GEMM: C[M][N] = A[M][K](bf16) @ BT[N][K](bf16)^T + bias ----------------
template<bool OUT_BF16>
__global__ __launch_bounds__(256) void k_gemm_bt(const unsigned short* __restrict__ A,
                                                 const unsigned short* __restrict__ BT,
                                                 const float* __restrict__ bias,
                                                 unsigned short* __restrict__ outb,
                                                 float* __restrict__ outf,
                                                 int M, int N, int K) {
    __shared__ unsigned short a_lds[2][128 * 32];
    __shared__ unsigned short b_lds[2][128 * 32];
    int tid = threadIdx.x;
    int w = tid >> 6, lane = tid & 63;
    int wr = w >> 1, wc = w & 1;
    int m0 = blockIdx.y * 128, n0 = blockIdx.x * 128;
    int lr = lane & 15, lg = lane >> 4;

    f32x4 acc[4][4] = {};

#define STAGE(buf, kt)                                                                              \
    {                                                                                               \
        _Pragma("unroll")                                                                           \
        for (int i = 0; i < 2; ++i) {                                                               \
            int g = i * 256 + tid;                                                                  \
            int row = g >> 2, kc = g & 3;                                                           \
            const unsigned short* srcA = A + (size_t)(m0 + row) * K + (kt) * 32 + kc * 8;           \
            const unsigned short* srcB = BT + (size_t)(n0 + row) * K + (kt) * 32 + kc * 8;          \
            unsigned short* dA = &a_lds[buf][(i * 256 + w * 64) * 8];                               \
            unsigned short* dB = &b_lds[buf][(i * 256 + w * 64) * 8];                               \
            __builtin_amdgcn_global_load_lds((const __attribute__((address_space(1))) void*)srcA,  \
                                             (__attribute__((address_space(3))) void*)dA, 16, 0, 0);\
            __builtin_amdgcn_global_load_lds((const __attribute__((address_space(1))) void*)srcB,  \
                                             (__attribute__((address_space(3))) void*)dB, 16, 0, 0);\
        }                                                                                           \
    }

    int NT = K >> 5;
    STAGE(0, 0);
    asm volatile("s_waitcnt vmcnt(0)" ::: "memory");
    __syncthreads();
    int cur = 0;
    for (int kt = 0; kt < NT; ++kt) {
        if (kt + 1 < NT) STAGE(cur ^ 1, kt + 1);
        int koff = lg * 8;
        short8 a[4], b[4];
#pragma unroll
        for (int i = 0; i < 4; ++i)
            a[i] = *(const short8*)&a_lds[cur][(wr * 64 + i * 16 + lr) * 32 + koff];
#pragma unroll
        for (int j = 0; j < 4; ++j)
            b[j] = *(const short8*)&b_lds[cur][(wc * 64 + j * 16 + lr) * 32 + koff];
#pragma unroll
        for (int i = 0; i < 4; ++i)
#pragma unroll
            for (int j = 0; j < 4; ++j)
                acc[i][j] = __builtin_amdgcn_mfma_f32_16x16x32_bf16(a[i], b[j], acc[i][j], 0, 0, 0);
        asm volatile("s_waitcnt vmcnt(0)" ::: "memory");
        __syncthreads();
        cur ^= 1;
    }
#undef STAGE

#pragma unroll
    for (int i = 0; i < 4; ++i) {
        int row = m0 + wr * 64 + i * 16 + lg * 4;
#pragma unroll
        for (int j = 0; j < 4; ++j) {
            int col = n0 + wc * 64 + j * 16 + lr;
            float bv = bias[col];
#pragma unroll
            for (int r = 0; r < 4; ++r) {
                float v = acc[i][j][r] + bv;
                if (OUT_BF16) outb[(size_t)(row + r) * N + col] = f2bf(v);
                else          outf[(size_t)(row + r) * N + col] = v;
            }
        }
    }
}

// ---------------- causal flash attention ----------------
// grid: 1024 blocks (16 q-tile pairs x 64 bh), 256 threads.
// Block handles q-tiles (pair) and (31-pair) sequentially -> uniform 33 kv iters.
// K/V tiles staged in LDS (double-buffered) with XOR swizzle byte^=(row&7)<<4.
#define SM_SCALE (0.125f * 1.44269504f)   /* 1/sqrt(64) * log2(e) */

__global__ __launch_bounds__(256, 4) void k_attn(const unsigned short* __restrict__ qkv,
                                                 const unsigned short* __restrict__ vt,
                                                 unsigned short* __restrict__ y) {
    __shared__ unsigned short k_lds[2][64 * 64];
    __shared__ unsigned short v_lds[2][64 * 64];
    __shared__ unsigned short p_lds[4][16 * 64];

    int tid = threadIdx.x;
    int w = tid >> 6, lane = tid & 63;
    int lr = lane & 15, lg = lane >> 4;

    // bijective XCD-chunk swizzle (1024 % 8 == 0)
    int bid = blockIdx.x;
    int bid2 = (bid & 7) * 128 + (bid >> 3);
    int bh = bid2 >> 4, pair = bid2 & 15;
    int b = bh >> 4, h = bh & 15;

    const unsigned short* kbase = qkv + (size_t)(b * T_) * C3_ + C_ + h * D_;
    const unsigned short* vtb = vt + (size_t)bh * D_ * T_;

#define ASTAGE(buf, kv0)                                                                            \
    {                                                                                               \
        _Pragma("unroll")                                                                           \
        for (int i = 0; i < 2; ++i) {                                                               \
            int slot = i * 256 + tid;                                                               \
            int row = slot >> 3;                                                                    \
            int colb = (slot & 7) << 4;                                                             \
            int scol = colb ^ ((row & 7) << 4);                                                     \
            const char* srcK = (const char*)(kbase + (size_t)((kv0) + row) * C3_) + scol;           \
            const char* srcV = (const char*)(vtb + (size_t)row * T_ + (kv0)) + scol;                \
            unsigned short* dK = &k_lds[buf][(i * 256 + w * 64) * 8];                               \
            unsigned short* dV = &v_lds[buf][(i * 256 + w * 64) * 8];                               \
            __builtin_amdgcn_global_load_lds((const __attribute__((address_space(1))) void*)srcK,  \
                                             (__attribute__((address_space(3))) void*)dK, 16, 0, 0);\
            __builtin_amdgcn_global_load_lds((const __attribute__((address_space(1))) void*)srcV,  \
                                             (__attribute__((address_space(3))) void*)dV, 16, 0, 0);\
        }                                                                                           \
    }

    for (int half = 0; half < 2; ++half) {
        int qt = half ? (31 - pair) : pair;
        int q0 = qt * 64;
        int ntiles = qt + 1;

        const unsigned short* qrow = qkv + (size_t)(b * T_ + q0 + w * 16 + lr) * C3_ + h * D_;
        short8 qf0 = *(const short8*)(qrow + lg * 8);
        short8 qf1 = *(const short8*)(qrow + 32 + lg * 8);

        f32x4 o[4] = {};
        float mreg[4] = {-1e30f, -1e30f, -1e30f, -1e30f};
        float ls[4] = {};
        int qg[4];
#pragma unroll
        for (int r = 0; r < 4; ++r) qg[r] = q0 + w * 16 + lg * 4 + r;

        ASTAGE(0, 0);
        asm volatile("s_waitcnt vmcnt(0)" ::: "memory");
        __syncthreads();
        int cur = 0;
        for (int kt = 0; kt < ntiles; ++kt) {
            if (kt + 1 < ntiles) ASTAGE(cur ^ 1, (kt + 1) * 64);

            // ---- QK^T ----
            f32x4 s[4] = {};
#pragma unroll
            for (int j = 0; j < 4; ++j) {
                int krow = j * 16 + lr;
                int sw = (krow & 7) << 4;
                const char* kr = (const char*)&k_lds[cur][krow * 64];
                short8 kf0 = *(const short8*)(kr + ((lg * 16) ^ sw));
                short8 kf1 = *(const short8*)(kr + ((64 + lg * 16) ^ sw));
                s[j] = __builtin_amdgcn_mfma_f32_16x16x32_bf16(qf0, kf0, s[j], 0, 0, 0);
                s[j] = __builtin_amdgcn_mfma_f32_16x16x32_bf16(qf1, kf1, s[j], 0, 0, 0);
            }

            // ---- masking + scale (log2 units) ----
            float p[4][4];
            float rmax[4] = {-INFINITY, -INFINITY, -INFINITY, -INFINITY};
            if (kt == ntiles - 1) {
#pragma unroll
                for (int j = 0; j < 4; ++j) {
                    int col = kt * 64 + j * 16 + lr;
#pragma unroll
                    for (int r = 0; r < 4; ++r) {
                        float sv = (col <= qg[r]) ? s[j][r] * SM_SCALE : -INFINITY;
                        p[j][r] = sv;
                        rmax[r] = fmaxf(rmax[r], sv);
                    }
                }
            } else {
#pragma unroll
                for (int j = 0; j < 4; ++j)
#pragma unroll
                    for (int r = 0; r < 4; ++r) {
                        float sv = s[j][r] * SM_SCALE;
                        p[j][r] = sv;
                        rmax[r] = fmaxf(rmax[r], sv);
                    }
            }

            // ---- online softmax (base-2) ----
#pragma unroll
            for (int r = 0; r < 4; ++r) {
#pragma unroll
                for (int mk = 1; mk < 16; mk <<= 1)
                    rmax[r] = fmaxf(rmax[r], __shfl_xor(rmax[r], mk));
                float mnew = fmaxf(mreg[r], rmax[r]);
                float sc = exp2f(mreg[r] - mnew);
                mreg[r] = mnew;
                float rsum = 0.f;
#pragma unroll
                for (int j = 0; j < 4; ++j) {
                    float pv = exp2f(p[j][r] - mnew);
                    p[j][r] = pv;
                    rsum += pv;
                }
#pragma unroll
                for (int mk = 1; mk < 16; mk <<= 1)
                    rsum += __shfl_xor(rsum, mk);
                ls[r] = ls[r] * sc + rsum;
#pragma unroll
                for (int dt = 0; dt < 4; ++dt) o[dt][r] *= sc;
            }

            // ---- P -> LDS (wave-private, swizzled; no barrier needed) ----
#pragma unroll
            for (int j = 0; j < 4; ++j)
#pragma unroll
                for (int r = 0; r < 4; ++r) {
                    int prow = lg * 4 + r;
                    char* pw = (char*)&p_lds[w][prow * 64];
                    *(unsigned short*)(pw + ((2 * (j * 16 + lr)) ^ ((prow & 7) << 4))) = f2bf(p[j][r]);
                }
            {
                int swr = (lr & 7) << 4;
                const char* pr = (const char*)&p_lds[w][lr * 64];
                short8 pa0 = *(const short8*)(pr + ((lg * 16) ^ swr));
                short8 pa1 = *(const short8*)(pr + ((64 + lg * 16) ^ swr));
                // ---- PV ----
#pragma unroll
                for (int dt = 0; dt < 4; ++dt) {
                    int vrow = dt * 16 + lr;
                    int sw = (vrow & 7) << 4;
                    const char* vr = (const char*)&v_lds[cur][vrow * 64];
                    short8 vf0 = *(const short8*)(vr + ((lg * 16) ^ sw));
                    short8 vf1 = *(const short8*)(vr + ((64 + lg * 16) ^ sw));
                    o[dt] = __builtin_amdgcn_mfma_f32_16x16x32_bf16(pa0, vf0, o[dt], 0, 0, 0);
                    o[dt] = __builtin_amdgcn_mfma_f32_16x16x32_bf16(pa1, vf1, o[dt], 0, 0, 0);
                }
            }

            asm volatile("s_waitcnt vmcnt(0)" ::: "memory");
            __syncthreads();
            cur ^= 1;
        }

#pragma unroll
        for (int r = 0; r < 4; ++r) {
            float inv = 1.0f / ls[r];
            int q = q0 + w * 16 + lg * 4 + r;
            unsigned short* yrow = y + (size_t)(b * T_ + q) * C_ + h * D_;
#pragma unroll
            for (int dt = 0; dt < 4; ++dt)
                yrow[dt * 16 + lr] = f2bf(o[dt][r] * inv);
        }
    }
#undef ASTAGE
}

extern "C" void kernel_launch(void* const* d_in, const int* in_sizes, int n_in,
                              void* d_out, int out_size, void* d_ws, size_t ws_size,
                              hipStream_t stream) {
    const float* x  = (const float*)d_in[0];
    const float* Wa = (const float*)d_in[1];
    const float* ba = (const float*)d_in[2];
    const float* Wp = (const float*)d_in[3];
    const float* bp = (const float*)d_in[4];
    float* out = (float*)d_out;

    char* ws = (char*)d_ws;
    unsigned short* xb  = (unsigned short*)(ws);                       // 16 MB
    unsigned short* wat = (unsigned short*)(ws + 16777216);            // 6 MB
    unsigned short* wpt = (unsigned short*)(ws + 23068672);            // 2 MB
    unsigned short* qkv = (unsigned short*)(ws + 25165824);            // 48 MB
    unsigned short* vt  = (unsigned short*)(ws + 75497472);            // 16 MB
    unsigned short* y   = xb;  // xb dead after GEMM1; reuse for attention output

    // x -> bf16
    k_cvt_bf16<<<8192, 256, 0, stream>>>(x, xb, (B_ * T_ * C_) / 4);
    // weights -> bf16 transposed
    k_wtrans<<<dim3(C3_ / 32, C_ / 32), dim3(32, 8), 0, stream>>>(Wa, wat, C_, C3_);
    k_wtrans<<<dim3(C_ / 32, C_ / 32), dim3(32, 8), 0, stream>>>(Wp, wpt, C_, C_);
    // qkv = x @ W_attn + b_attn   (bf16 out)
    k_gemm_bt<true><<<dim3(C3_ / 128, (B_ * T_) / 128), 256, 0, stream>>>(
        xb, wat, ba, qkv, nullptr, B_ * T_, C3_, C_);
    // v -> vt[bh][d][t]
    k_prep_vt<<<dim3(T_ / 64, B_ * H_), 256, 0, stream>>>(qkv, vt);
    // attention
    k_attn<<<1024, 256, 0, stream>>>(qkv, vt, y);
    // out = y @ W_proj + b_proj   (fp32 out)
    k_gemm_bt<false><<<dim3(C_ / 128, (B_ * T_) / 128), 256, 0, stream>>>(
        y, wpt, bp, nullptr, out, B_ * T_, C_, C_);
}

// Round 3
// 199.310 us; speedup vs baseline: 3.0309x; 1.2282x over previous
//
#include <hip/hip_runtime.h>
#include <stdint.h>

typedef __attribute__((ext_vector_type(8))) short short8;
typedef __attribute__((ext_vector_type(4))) float f32x4;

#define B_ 4
#define T_ 2048
#define C_ 1024
#define H_ 16
#define D_ 64
#define C3_ 3072

__device__ __forceinline__ unsigned short f2bf(float f) {
    union { float f; uint32_t u; } v; v.f = f;
    uint32_t r = v.u + 0x7FFFu + ((v.u >> 16) & 1u);
    return (unsigned short)(r >> 16);
}

__device__ __forceinline__ uint32_t pk_bf16(float lo, float hi) {
    uint32_t r;
    asm("v_cvt_pk_bf16_f32 %0, %1, %2" : "=v"(r) : "v"(lo), "v"(hi));
    return r;
}

// ---------------- fp32 -> bf16 elementwise ----------------
__global__ void k_cvt_bf16(const float* __restrict__ in, unsigned short* __restrict__ out, int n4) {
    int i = blockIdx.x * blockDim.x + threadIdx.x;
    if (i >= n4) return;
    float4 v = ((const float4*)in)[i];
    unsigned short o0 = f2bf(v.x), o1 = f2bf(v.y), o2 = f2bf(v.z), o3 = f2bf(v.w);
    unsigned long long packed = (unsigned long long)o0 | ((unsigned long long)o1 << 16)
        | ((unsigned long long)o2 << 32) | ((unsigned long long)o3 << 48);
    *(unsigned long long*)(out + (size_t)i * 4) = packed;
}

// ---------------- W[K][N] fp32 -> WT[N][K] bf16 ----------------
__global__ void k_wtrans(const float* __restrict__ W, unsigned short* __restrict__ WT, int K, int N) {
    __shared__ float t[32][33];
    int n0 = blockIdx.x * 32, k0 = blockIdx.y * 32;
    int tx = threadIdx.x, ty = threadIdx.y; // (32,8)
#pragma unroll
    for (int i = 0; i < 4; ++i)
        t[ty + i * 8][tx] = W[(size_t)(k0 + ty + i * 8) * N + n0 + tx];
    __syncthreads();
#pragma unroll
    for (int i = 0; i < 4; ++i)
        WT[(size_t)(n0 + ty + i * 8) * K + k0 + tx] = f2bf(t[tx][ty + i * 8]);
}

// ---------------- extract V head-major transposed: vt[bh][d][t] ----------------
__global__ void k_prep_vt(const unsigned short* __restrict__ qkv, unsigned short* __restrict__ vt) {
    int bh = blockIdx.y; int b = bh >> 4, h = bh & 15;
    int t0 = blockIdx.x * 64;
    __shared__ unsigned short tile[64][72];
    int tid = threadIdx.x;
    int r = tid >> 3;          // 0..31
    int c = (tid & 7) * 8;     // 0..56
#pragma unroll
    for (int rr = 0; rr < 64; rr += 32) {
        const unsigned short* src = qkv + (size_t)(b * T_ + t0 + r + rr) * C3_ + 2 * C_ + h * D_ + c;
        short8 v = *(const short8*)src;
#pragma unroll
        for (int j = 0; j < 8; ++j) tile[r + rr][c + j] = (unsigned short)v[j];
    }
    __syncthreads();
#pragma unroll
    for (int rr = 0; rr < 64; rr += 32) {
        int d = r + rr;
        short8 sv;
#pragma unroll
        for (int j = 0; j < 8; ++j) sv[j] = (short)tile[c + j][d];
        *(short8*)(vt + (size_t)bh * D_ * T_ + (size_t)d * T_ + t0 + c) = sv;
    }
}

// ---------------- GEMM: C[M][N] = A[M][K](bf16) @ BT[N][K](bf16)^T + bias ----------------
template<bool OUT_BF16>
__global__ __launch_bounds__(256) void k_gemm_bt(const unsigned short* __restrict__ A,
                                                 const unsigned short* __restrict__ BT,
                                                 const float* __restrict__ bias,
                                                 unsigned short* __restrict__ outb,
                                                 float* __restrict__ outf,
                                                 int M, int N, int K) {
    __shared__ unsigned short a_lds[2][128 * 32];
    __shared__ unsigned short b_lds[2][128 * 32];
    int tid = threadIdx.x;
    int w = tid >> 6, lane = tid & 63;
    int wr = w >> 1, wc = w & 1;
    int m0 = blockIdx.y * 128, n0 = blockIdx.x * 128;
    int lr = lane & 15, lg = lane >> 4;

    f32x4 acc[4][4] = {};

#define STAGE(buf, kt)                                                                              \
    {                                                                                               \
        _Pragma("unroll")                                                                           \
        for (int i = 0; i < 2; ++i) {                                                               \
            int g = i * 256 + tid;                                                                  \
            int row = g >> 2, kc = g & 3;                                                           \
            const unsigned short* srcA = A + (size_t)(m0 + row) * K + (kt) * 32 + kc * 8;           \
            const unsigned short* srcB = BT + (size_t)(n0 + row) * K + (kt) * 32 + kc * 8;          \
            unsigned short* dA = &a_lds[buf][(i * 256 + w * 64) * 8];                               \
            unsigned short* dB = &b_lds[buf][(i * 256 + w * 64) * 8];                               \
            __builtin_amdgcn_global_load_lds((const __attribute__((address_space(1))) void*)srcA,  \
                                             (__attribute__((address_space(3))) void*)dA, 16, 0, 0);\
            __builtin_amdgcn_global_load_lds((const __attribute__((address_space(1))) void*)srcB,  \
                                             (__attribute__((address_space(3))) void*)dB, 16, 0, 0);\
        }                                                                                           \
    }

    int NT = K >> 5;
    STAGE(0, 0);
    asm volatile("s_waitcnt vmcnt(0)" ::: "memory");
    __syncthreads();
    int cur = 0;
    for (int kt = 0; kt < NT; ++kt) {
        if (kt + 1 < NT) STAGE(cur ^ 1, kt + 1);
        int koff = lg * 8;
        short8 a[4], b[4];
#pragma unroll
        for (int i = 0; i < 4; ++i)
            a[i] = *(const short8*)&a_lds[cur][(wr * 64 + i * 16 + lr) * 32 + koff];
#pragma unroll
        for (int j = 0; j < 4; ++j)
            b[j] = *(const short8*)&b_lds[cur][(wc * 64 + j * 16 + lr) * 32 + koff];
#pragma unroll
        for (int i = 0; i < 4; ++i)
#pragma unroll
            for (int j = 0; j < 4; ++j)
                acc[i][j] = __builtin_amdgcn_mfma_f32_16x16x32_bf16(a[i], b[j], acc[i][j], 0, 0, 0);
        asm volatile("s_waitcnt vmcnt(0)" ::: "memory");
        __syncthreads();
        cur ^= 1;
    }
#undef STAGE

#pragma unroll
    for (int i = 0; i < 4; ++i) {
        int row = m0 + wr * 64 + i * 16 + lg * 4;
#pragma unroll
        for (int j = 0; j < 4; ++j) {
            int col = n0 + wc * 64 + j * 16 + lr;
            float bv = bias[col];
#pragma unroll
            for (int r = 0; r < 4; ++r) {
                float v = acc[i][j][r] + bv;
                if (OUT_BF16) outb[(size_t)(row + r) * N + col] = f2bf(v);
                else          outf[(size_t)(row + r) * N + col] = v;
            }
        }
    }
}

// ---------------- causal flash attention (swapped QK^T, in-lane softmax) ----------------
#define SM_SCALE (0.125f * 1.44269504f)   /* 1/sqrt(64) * log2(e) */

__global__ __launch_bounds__(256, 4) void k_attn(const unsigned short* __restrict__ qkv,
                                                 const unsigned short* __restrict__ vt,
                                                 unsigned short* __restrict__ y) {
    __shared__ unsigned short k_lds[2][64 * 64];
    __shared__ unsigned short v_lds[2][64 * 64];
    __shared__ unsigned short p_lds[4][16 * 64];   // [wave][q][k], XOR-swizzled

    int tid = threadIdx.x;
    int w = tid >> 6, lane = tid & 63;
    int lr = lane & 15, lg = lane >> 4;

    // bijective XCD-chunk swizzle (1024 % 8 == 0)
    int bid = blockIdx.x;
    int bid2 = (bid & 7) * 128 + (bid >> 3);
    int bh = bid2 >> 4, pair = bid2 & 15;
    int b = bh >> 4, h = bh & 15;

    const unsigned short* kbase = qkv + (size_t)(b * T_) * C3_ + C_ + h * D_;
    const unsigned short* vtb = vt + (size_t)bh * D_ * T_;

#define ASTAGE(buf, kv0)                                                                            \
    {                                                                                               \
        _Pragma("unroll")                                                                           \
        for (int i = 0; i < 2; ++i) {                                                               \
            int slot = i * 256 + tid;                                                               \
            int row = slot >> 3;                                                                    \
            int colb = (slot & 7) << 4;                                                             \
            int scol = colb ^ ((row & 7) << 4);                                                     \
            const char* srcK = (const char*)(kbase + (size_t)((kv0) + row) * C3_) + scol;           \
            const char* srcV = (const char*)(vtb + (size_t)row * T_ + (kv0)) + scol;                \
            unsigned short* dK = &k_lds[buf][(i * 256 + w * 64) * 8];                               \
            unsigned short* dV = &v_lds[buf][(i * 256 + w * 64) * 8];                               \
            __builtin_amdgcn_global_load_lds((const __attribute__((address_space(1))) void*)srcK,  \
                                             (__attribute__((address_space(3))) void*)dK, 16, 0, 0);\
            __builtin_amdgcn_global_load_lds((const __attribute__((address_space(1))) void*)srcV,  \
                                             (__attribute__((address_space(3))) void*)dV, 16, 0, 0);\
        }                                                                                           \
    }

    for (int half = 0; half < 2; ++half) {
        int qt = half ? (31 - pair) : pair;
        int q0 = qt * 64;
        int ntiles = qt + 1;

        const unsigned short* qrow = qkv + (size_t)(b * T_ + q0 + w * 16 + lr) * C3_ + h * D_;
        short8 qf0 = *(const short8*)(qrow + lg * 8);
        short8 qf1 = *(const short8*)(qrow + 32 + lg * 8);

        f32x4 o[4] = {};
        float mreg = -1e30f;   // softmax state for q = q0 + w*16 + lr (log2-scaled units)
        float ls = 0.f;
        int qv = q0 + w * 16 + lr;

        ASTAGE(0, 0);
        asm volatile("s_waitcnt vmcnt(0)" ::: "memory");
        __syncthreads();
        int cur = 0;
        for (int kt = 0; kt < ntiles; ++kt) {
            if (kt + 1 < ntiles) ASTAGE(cur ^ 1, (kt + 1) * 64);

            // ---- QK^T (swapped): s[j][r] = S[k = kt*64 + j*16 + lg*4 + r][q = qv] ----
            f32x4 s[4] = {};
#pragma unroll
            for (int j = 0; j < 4; ++j) {
                int krow = j * 16 + lr;
                int sw = (krow & 7) << 4;
                const char* kr = (const char*)&k_lds[cur][krow * 64];
                short8 kf0 = *(const short8*)(kr + ((lg * 16) ^ sw));
                short8 kf1 = *(const short8*)(kr + ((64 + lg * 16) ^ sw));
                s[j] = __builtin_amdgcn_mfma_f32_16x16x32_bf16(kf0, qf0, s[j], 0, 0, 0);
                s[j] = __builtin_amdgcn_mfma_f32_16x16x32_bf16(kf1, qf1, s[j], 0, 0, 0);
            }

            // ---- causal mask (diagonal tile only) ----
            if (kt == ntiles - 1) {
                int kb = kt * 64 + lg * 4 - qv;
#pragma unroll
                for (int j = 0; j < 4; ++j)
#pragma unroll
                    for (int r = 0; r < 4; ++r)
                        if (kb + j * 16 + r > 0) s[j][r] = -INFINITY;
            }

            // ---- tile max: in-lane over 16 regs + 2 cross-lane ----
            float pm = -INFINITY;
#pragma unroll
            for (int j = 0; j < 4; ++j)
#pragma unroll
                for (int r = 0; r < 4; ++r) pm = fmaxf(pm, s[j][r]);
            pm = fmaxf(pm, __shfl_xor(pm, 16));
            pm = fmaxf(pm, __shfl_xor(pm, 32));
            pm *= SM_SCALE;

            // ---- defer-max rescale (THR = 8 in log2 units) ----
            if (!__all(pm <= mreg + 8.0f)) {
                float mn = fmaxf(mreg, pm);
                float sc = exp2f(mreg - mn);
                mreg = mn;
                ls *= sc;
#pragma unroll
                for (int r = 0; r < 4; ++r) {
                    float sct = __shfl(sc, lg * 4 + r, 64);
                    o[0][r] *= sct; o[1][r] *= sct; o[2][r] *= sct; o[3][r] *= sct;
                }
            }

            // ---- exponentials + in-lane sum ----
            float p[4][4];
            float rs = 0.f;
#pragma unroll
            for (int j = 0; j < 4; ++j)
#pragma unroll
                for (int r = 0; r < 4; ++r) {
                    float pv = exp2f(fmaf(s[j][r], SM_SCALE, -mreg));
                    p[j][r] = pv;
                    rs += pv;
                }
            rs += __shfl_xor(rs, 16);
            rs += __shfl_xor(rs, 32);
            ls += rs;

            // ---- P -> LDS [q][k] (packed b64 writes, swizzled), read back as A-frags ----
            {
                char* pb = (char*)&p_lds[w][0];
                int swq = (lr & 7) << 4;
#pragma unroll
                for (int j = 0; j < 4; ++j) {
                    uint2 uu;
                    uu.x = pk_bf16(p[j][0], p[j][1]);
                    uu.y = pk_bf16(p[j][2], p[j][3]);
                    *(uint2*)(pb + lr * 128 + ((j * 32 + lg * 8) ^ swq)) = uu;
                }
                short8 pa0 = *(const short8*)(pb + lr * 128 + ((lg * 16) ^ swq));
                short8 pa1 = *(const short8*)(pb + lr * 128 + ((64 + lg * 16) ^ swq));

                // ---- PV ----
#pragma unroll
                for (int dt = 0; dt < 4; ++dt) {
                    int vrow = dt * 16 + lr;
                    int sw = (vrow & 7) << 4;
                    const char* vr = (const char*)&v_lds[cur][vrow * 64];
                    short8 vf0 = *(const short8*)(vr + ((lg * 16) ^ sw));
                    short8 vf1 = *(const short8*)(vr + ((64 + lg * 16) ^ sw));
                    o[dt] = __builtin_amdgcn_mfma_f32_16x16x32_bf16(pa0, vf0, o[dt], 0, 0, 0);
                    o[dt] = __builtin_amdgcn_mfma_f32_16x16x32_bf16(pa1, vf1, o[dt], 0, 0, 0);
                }
            }

            asm volatile("s_waitcnt vmcnt(0)" ::: "memory");
            __syncthreads();
            cur ^= 1;
        }

        // ---- normalize + store (O rows live at q = q0 + w*16 + lg*4 + r) ----
#pragma unroll
        for (int r = 0; r < 4; ++r) {
            float lst = __shfl(ls, lg * 4 + r, 64);
            float inv = 1.0f / lst;
            int q = q0 + w * 16 + lg * 4 + r;
            unsigned short* yrow = y + (size_t)(b * T_ + q) * C_ + h * D_;
#pragma unroll
            for (int dt = 0; dt < 4; ++dt)
                yrow[dt * 16 + lr] = f2bf(o[dt][r] * inv);
        }
    }
#undef ASTAGE
}

extern "C" void kernel_launch(void* const* d_in, const int* in_sizes, int n_in,
                              void* d_out, int out_size, void* d_ws, size_t ws_size,
                              hipStream_t stream) {
    const float* x  = (const float*)d_in[0];
    const float* Wa = (const float*)d_in[1];
    const float* ba = (const float*)d_in[2];
    const float* Wp = (const float*)d_in[3];
    const float* bp = (const float*)d_in[4];
    float* out = (float*)d_out;

    char* ws = (char*)d_ws;
    unsigned short* xb  = (unsigned short*)(ws);                       // 16 MB
    unsigned short* wat = (unsigned short*)(ws + 16777216);            // 6 MB
    unsigned short* wpt = (unsigned short*)(ws + 23068672);            // 2 MB
    unsigned short* qkv = (unsigned short*)(ws + 25165824);            // 48 MB
    unsigned short* vt  = (unsigned short*)(ws + 75497472);            // 16 MB
    unsigned short* y   = xb;  // xb dead after GEMM1; reuse for attention output

    // x -> bf16
    k_cvt_bf16<<<8192, 256, 0, stream>>>(x, xb, (B_ * T_ * C_) / 4);
    // weights -> bf16 transposed
    k_wtrans<<<dim3(C3_ / 32, C_ / 32), dim3(32, 8), 0, stream>>>(Wa, wat, C_, C3_);
    k_wtrans<<<dim3(C_ / 32, C_ / 32), dim3(32, 8), 0, stream>>>(Wp, wpt, C_, C_);
    // qkv = x @ W_attn + b_attn   (bf16 out)
    k_gemm_bt<true><<<dim3(C3_ / 128, (B_ * T_) / 128), 256, 0, stream>>>(
        xb, wat, ba, qkv, nullptr, B_ * T_, C3_, C_);
    // v -> vt[bh][d][t]
    k_prep_vt<<<dim3(T_ / 64, B_ * H_), 256, 0, stream>>>(qkv, vt);
    // attention
    k_attn<<<1024, 256, 0, stream>>>(qkv, vt, y);
    // out = y @ W_proj + b_proj   (fp32 out)
    k_gemm_bt<false><<<dim3(C_ / 128, (B_ * T_) / 128), 256, 0, stream>>>(
        y, wpt, bp, nullptr, out, B_ * T_, C_, C_);
}

// Round 4
// 197.777 us; speedup vs baseline: 3.0544x; 1.0078x over previous
//
#include <hip/hip_runtime.h>
#include <stdint.h>

typedef __attribute__((ext_vector_type(8))) short short8;
typedef __attribute__((ext_vector_type(4))) float f32x4;
typedef __attribute__((ext_vector_type(2))) unsigned int uint2v;

#define B_ 4
#define T_ 2048
#define C_ 1024
#define H_ 16
#define D_ 64
#define C3_ 3072

#define AS1 __attribute__((address_space(1)))
#define AS3 __attribute__((address_space(3)))

__device__ __forceinline__ unsigned short f2bf(float f) {
    union { float f; uint32_t u; } v; v.f = f;
    uint32_t r = v.u + 0x7FFFu + ((v.u >> 16) & 1u);
    return (unsigned short)(r >> 16);
}

__device__ __forceinline__ uint32_t pk_bf16(float lo, float hi) {
    uint32_t r;
    asm("v_cvt_pk_bf16_f32 %0, %1, %2" : "=v"(r) : "v"(lo), "v"(hi));
    return r;
}

// ---------------- fp32 -> bf16 elementwise ----------------
__global__ void k_cvt_bf16(const float* __restrict__ in, unsigned short* __restrict__ out, int n4) {
    int i = blockIdx.x * blockDim.x + threadIdx.x;
    if (i >= n4) return;
    float4 v = ((const float4*)in)[i];
    unsigned short o0 = f2bf(v.x), o1 = f2bf(v.y), o2 = f2bf(v.z), o3 = f2bf(v.w);
    unsigned long long packed = (unsigned long long)o0 | ((unsigned long long)o1 << 16)
        | ((unsigned long long)o2 << 32) | ((unsigned long long)o3 << 48);
    *(unsigned long long*)(out + (size_t)i * 4) = packed;
}

// ---------------- W[K][N] fp32 -> WT[N][K] bf16 ----------------
__global__ void k_wtrans(const float* __restrict__ W, unsigned short* __restrict__ WT, int K, int N) {
    __shared__ float t[32][33];
    int n0 = blockIdx.x * 32, k0 = blockIdx.y * 32;
    int tx = threadIdx.x, ty = threadIdx.y; // (32,8)
#pragma unroll
    for (int i = 0; i < 4; ++i)
        t[ty + i * 8][tx] = W[(size_t)(k0 + ty + i * 8) * N + n0 + tx];
    __syncthreads();
#pragma unroll
    for (int i = 0; i < 4; ++i)
        WT[(size_t)(n0 + ty + i * 8) * K + k0 + tx] = f2bf(t[tx][ty + i * 8]);
}

// ---------------- extract V head-major transposed: vt[bh][d][t] ----------------
__global__ void k_prep_vt(const unsigned short* __restrict__ qkv, unsigned short* __restrict__ vt) {
    int bh = blockIdx.y; int b = bh >> 4, h = bh & 15;
    int t0 = blockIdx.x * 64;
    __shared__ unsigned short tile[64][72];
    int tid = threadIdx.x;
    int r = tid >> 3;          // 0..31
    int c = (tid & 7) * 8;     // 0..56
#pragma unroll
    for (int rr = 0; rr < 64; rr += 32) {
        const unsigned short* src = qkv + (size_t)(b * T_ + t0 + r + rr) * C3_ + 2 * C_ + h * D_ + c;
        short8 v = *(const short8*)src;
#pragma unroll
        for (int j = 0; j < 8; ++j) tile[r + rr][c + j] = (unsigned short)v[j];
    }
    __syncthreads();
#pragma unroll
    for (int rr = 0; rr < 64; rr += 32) {
        int d = r + rr;
        short8 sv;
#pragma unroll
        for (int j = 0; j < 8; ++j) sv[j] = (short)tile[c + j][d];
        *(short8*)(vt + (size_t)bh * D_ * T_ + (size_t)d * T_ + t0 + c) = sv;
    }
}

// ---------------- GEMM: C[M][N] = A[M][K](bf16) @ BT[N][K](bf16)^T + bias ----------------
template<bool OUT_BF16>
__global__ __launch_bounds__(256) void k_gemm_bt(const unsigned short* __restrict__ A,
                                                 const unsigned short* __restrict__ BT,
                                                 const float* __restrict__ bias,
                                                 unsigned short* __restrict__ outb,
                                                 float* __restrict__ outf,
                                                 int M, int N, int K) {
    __shared__ unsigned short a_lds[2][128 * 32];
    __shared__ unsigned short b_lds[2][128 * 32];
    int tid = threadIdx.x;
    int w = tid >> 6, lane = tid & 63;
    int wr = w >> 1, wc = w & 1;
    int m0 = blockIdx.y * 128, n0 = blockIdx.x * 128;
    int lr = lane & 15, lg = lane >> 4;

    f32x4 acc[4][4] = {};

#define STAGE(buf, kt)                                                                              \
    {                                                                                               \
        _Pragma("unroll")                                                                           \
        for (int i = 0; i < 2; ++i) {                                                               \
            int g = i * 256 + tid;                                                                  \
            int row = g >> 2, kc = g & 3;                                                           \
            const unsigned short* srcA = A + (size_t)(m0 + row) * K + (kt) * 32 + kc * 8;           \
            const unsigned short* srcB = BT + (size_t)(n0 + row) * K + (kt) * 32 + kc * 8;          \
            unsigned short* dA = &a_lds[buf][(i * 256 + w * 64) * 8];                               \
            unsigned short* dB = &b_lds[buf][(i * 256 + w * 64) * 8];                               \
            __builtin_amdgcn_global_load_lds((const AS1 void*)srcA,                                 \
                                             (AS3 void*)dA, 16, 0, 0);                              \
            __builtin_amdgcn_global_load_lds((const AS1 void*)srcB,                                 \
                                             (AS3 void*)dB, 16, 0, 0);                              \
        }                                                                                           \
    }

    int NT = K >> 5;
    STAGE(0, 0);
    asm volatile("s_waitcnt vmcnt(0)" ::: "memory");
    __syncthreads();
    int cur = 0;
    for (int kt = 0; kt < NT; ++kt) {
        if (kt + 1 < NT) STAGE(cur ^ 1, kt + 1);
        int koff = lg * 8;
        short8 a[4], b[4];
#pragma unroll
        for (int i = 0; i < 4; ++i)
            a[i] = *(const short8*)&a_lds[cur][(wr * 64 + i * 16 + lr) * 32 + koff];
#pragma unroll
        for (int j = 0; j < 4; ++j)
            b[j] = *(const short8*)&b_lds[cur][(wc * 64 + j * 16 + lr) * 32 + koff];
#pragma unroll
        for (int i = 0; i < 4; ++i)
#pragma unroll
            for (int j = 0; j < 4; ++j)
                acc[i][j] = __builtin_amdgcn_mfma_f32_16x16x32_bf16(a[i], b[j], acc[i][j], 0, 0, 0);
        asm volatile("s_waitcnt vmcnt(0)" ::: "memory");
        __syncthreads();
        cur ^= 1;
    }
#undef STAGE

#pragma unroll
    for (int i = 0; i < 4; ++i) {
        int row = m0 + wr * 64 + i * 16 + lg * 4;
#pragma unroll
        for (int j = 0; j < 4; ++j) {
            int col = n0 + wc * 64 + j * 16 + lr;
            float bv = bias[col];
#pragma unroll
            for (int r = 0; r < 4; ++r) {
                float v = acc[i][j][r] + bv;
                if (OUT_BF16) outb[(size_t)(row + r) * N + col] = f2bf(v);
                else          outf[(size_t)(row + r) * N + col] = v;
            }
        }
    }
}

// ---------------- causal flash attention (swapped QK^T, imm-folded LDS addressing) ----------------
// LDS arena layout (bytes):
//   [0,8192)      K buf0      [8192,16384)   K buf1
//   [16384,24576) V buf0      [24576,32768)  V buf1
//   [32768,40960) P per-wave (w*2048), conflict-free half-parity swizzle
#define SM_SCALE (0.125f * 1.44269504f)   /* 1/sqrt(64) * log2(e) */

__global__ __launch_bounds__(256, 4) void k_attn(const unsigned short* __restrict__ qkv,
                                                 const unsigned short* __restrict__ vt,
                                                 unsigned short* __restrict__ y) {
    __shared__ char arena[40960];
    int tid = threadIdx.x;
    int w = tid >> 6, lane = tid & 63;
    int lr = lane & 15, lg = lane >> 4;

    // bijective XCD-chunk swizzle (1024 % 8 == 0)
    int bid = blockIdx.x;
    int bid2 = (bid & 7) * 128 + (bid >> 3);
    int bh = bid2 >> 4, pair = bid2 & 15;
    int b = bh >> 4, h = bh & 15;

    const unsigned short* kbase = qkv + (size_t)(b * T_) * C3_ + C_ + h * D_;
    const unsigned short* vtb = vt + (size_t)bh * D_ * T_;

    // --- precomputed LDS addresses (tile-invariant) ---
    int sw_ = (lr & 7) << 4;
    int RB0 = lr * 128 + ((lg * 16) ^ sw_);   // K/V frag base (imm: arrayoff + buf + j*2048)
    int RB1 = RB0 ^ 64;
    int jl = (lr >> 1) & 3;
    int pbase = 32768 + w * 2048 + lr * 128
              + ((((lg >> 1) ^ (lr & 1)) << 4) | (((lg & 1) ^ (lr >> 3)) << 3));
    int pwa[4];
#pragma unroll
    for (int j = 0; j < 4; ++j) pwa[j] = pbase + ((j ^ jl) << 5);
    int prd0 = 32768 + w * 2048 + lr * 128 + ((lg ^ (lr & 7)) << 4);
    int prd1 = prd0 ^ 64;
    bool hswap = (lr & 8) != 0;

    // --- global stage sources (loop-carried pointers) ---
    int row0 = tid >> 3, row1 = 32 + (tid >> 3);
    int scol0 = ((tid & 7) << 4) ^ ((row0 & 7) << 4);
    int scol1 = ((tid & 7) << 4) ^ ((row1 & 7) << 4);

    const char *sK0, *sK1, *sV0, *sV1;

#define STAGE(LDSOFF)                                                                                   \
    {                                                                                                   \
        __builtin_amdgcn_global_load_lds((const AS1 void*)sK0, (AS3 void*)(arena + (LDSOFF) + w * 1024), 16, 0, 0);          \
        __builtin_amdgcn_global_load_lds((const AS1 void*)sK1, (AS3 void*)(arena + (LDSOFF) + 4096 + w * 1024), 16, 0, 0);   \
        __builtin_amdgcn_global_load_lds((const AS1 void*)sV0, (AS3 void*)(arena + 16384 + (LDSOFF) + w * 1024), 16, 0, 0);  \
        __builtin_amdgcn_global_load_lds((const AS1 void*)sV1, (AS3 void*)(arena + 16384 + (LDSOFF) + 4096 + w * 1024), 16, 0, 0); \
        sK0 += 64 * C3_ * 2; sK1 += 64 * C3_ * 2; sV0 += 128; sV1 += 128;                               \
    }

#define COMPUTE(LDSOFF, KT)                                                                             \
    {                                                                                                   \
        f32x4 s[4];                                                                                     \
        _Pragma("unroll")                                                                               \
        for (int j = 0; j < 4; ++j) {                                                                   \
            short8 kf0 = *(const short8*)(arena + RB0 + (LDSOFF) + j * 2048);                           \
            short8 kf1 = *(const short8*)(arena + RB1 + (LDSOFF) + j * 2048);                           \
            f32x4 z = {};                                                                               \
            z = __builtin_amdgcn_mfma_f32_16x16x32_bf16(kf0, qf0, z, 0, 0, 0);                          \
            s[j] = __builtin_amdgcn_mfma_f32_16x16x32_bf16(kf1, qf1, s[j] = z, 0, 0, 0);                \
        }                                                                                               \
        if ((KT) == ntiles - 1) {                                                                       \
            int kb = (KT) * 64 + lg * 4 - qv;                                                           \
            _Pragma("unroll")                                                                           \
            for (int j = 0; j < 4; ++j)                                                                 \
                _Pragma("unroll")                                                                       \
                for (int r = 0; r < 4; ++r)                                                             \
                    if (kb + j * 16 + r > 0) s[j][r] = -INFINITY;                                       \
        }                                                                                               \
        float a0 = fmaxf(fmaxf(s[0][0], s[0][1]), s[0][2]);                                             \
        float a1 = fmaxf(fmaxf(s[0][3], s[1][0]), s[1][1]);                                             \
        float a2 = fmaxf(fmaxf(s[1][2], s[1][3]), s[2][0]);                                             \
        float a3 = fmaxf(fmaxf(s[2][1], s[2][2]), s[2][3]);                                             \
        float a4 = fmaxf(fmaxf(s[3][0], s[3][1]), s[3][2]);                                             \
        float pm = fmaxf(fmaxf(fmaxf(a0, a1), a2), fmaxf(fmaxf(a3, a4), s[3][3]));                      \
        pm = fmaxf(pm, __shfl_xor(pm, 16));                                                             \
        pm = fmaxf(pm, __shfl_xor(pm, 32));                                                             \
        pm *= SM_SCALE;                                                                                 \
        if (!__all(pm <= mreg + 8.0f)) {                                                                \
            float mn = fmaxf(mreg, pm);                                                                 \
            float sc = exp2f(mreg - mn);                                                                \
            mreg = mn; ls *= sc;                                                                        \
            _Pragma("unroll")                                                                           \
            for (int r = 0; r < 4; ++r) {                                                               \
                float sct = __shfl(sc, lg * 4 + r, 64);                                                 \
                o[0][r] *= sct; o[1][r] *= sct; o[2][r] *= sct; o[3][r] *= sct;                         \
            }                                                                                           \
        }                                                                                               \
        float rs = 0.f;                                                                                 \
        _Pragma("unroll")                                                                               \
        for (int j = 0; j < 4; ++j)                                                                     \
            _Pragma("unroll")                                                                           \
            for (int r = 0; r < 4; ++r) {                                                               \
                float pv = exp2f(fmaf(s[j][r], SM_SCALE, -mreg));                                       \
                s[j][r] = pv; rs += pv;                                                                 \
            }                                                                                           \
        rs += __shfl_xor(rs, 16);                                                                       \
        rs += __shfl_xor(rs, 32);                                                                       \
        ls += rs;                                                                                       \
        _Pragma("unroll")                                                                               \
        for (int j = 0; j < 4; ++j) {                                                                   \
            uint2v W;                                                                                   \
            W[0] = pk_bf16(s[j][0], s[j][1]);                                                           \
            W[1] = pk_bf16(s[j][2], s[j][3]);                                                           \
            *(uint2v*)(arena + pwa[j]) = W;                                                             \
        }                                                                                               \
        short8 pv0 = *(const short8*)(arena + prd0);                                                    \
        short8 pv1 = *(const short8*)(arena + prd1);                                                    \
        short8 t0 = {pv0[4], pv0[5], pv0[6], pv0[7], pv0[0], pv0[1], pv0[2], pv0[3]};                   \
        short8 t1 = {pv1[4], pv1[5], pv1[6], pv1[7], pv1[0], pv1[1], pv1[2], pv1[3]};                   \
        short8 pa0 = hswap ? t0 : pv0;                                                                  \
        short8 pa1 = hswap ? t1 : pv1;                                                                  \
        _Pragma("unroll")                                                                               \
        for (int dt = 0; dt < 4; ++dt) {                                                                \
            short8 vf0 = *(const short8*)(arena + RB0 + 16384 + (LDSOFF) + dt * 2048);                  \
            short8 vf1 = *(const short8*)(arena + RB1 + 16384 + (LDSOFF) + dt * 2048);                  \
            o[dt] = __builtin_amdgcn_mfma_f32_16x16x32_bf16(pa0, vf0, o[dt], 0, 0, 0);                  \
            o[dt] = __builtin_amdgcn_mfma_f32_16x16x32_bf16(pa1, vf1, o[dt], 0, 0, 0);                  \
        }                                                                                               \
    }

#pragma unroll 1
    for (int half = 0; half < 2; ++half) {
        int qt = half ? (31 - pair) : pair;
        int q0 = qt * 64;
        int ntiles = qt + 1;

        const unsigned short* qrow = qkv + (size_t)(b * T_ + q0 + w * 16 + lr) * C3_ + h * D_;
        short8 qf0 = *(const short8*)(qrow + lg * 8);
        short8 qf1 = *(const short8*)(qrow + 32 + lg * 8);

        f32x4 o[4] = {};
        float mreg = -1e30f;   // softmax state for q = q0 + w*16 + lr (log2 units)
        float ls = 0.f;
        int qv = q0 + w * 16 + lr;

        sK0 = (const char*)(kbase + (size_t)row0 * C3_) + scol0;
        sK1 = (const char*)(kbase + (size_t)row1 * C3_) + scol1;
        sV0 = (const char*)(vtb + (size_t)row0 * T_) + scol0;
        sV1 = (const char*)(vtb + (size_t)row1 * T_) + scol1;

        STAGE(0);
        asm volatile("s_waitcnt vmcnt(0)" ::: "memory");
        __syncthreads();

#pragma unroll 1
        for (int kt = 0; kt < ntiles; kt += 2) {
            if (kt + 1 < ntiles) STAGE(8192);
            COMPUTE(0, kt);
            asm volatile("s_waitcnt vmcnt(0)" ::: "memory");
            __syncthreads();
            if (kt + 1 < ntiles) {
                if (kt + 2 < ntiles) STAGE(0);
                COMPUTE(8192, kt + 1);
                asm volatile("s_waitcnt vmcnt(0)" ::: "memory");
                __syncthreads();
            }
        }

        // ---- normalize + store (O rows live at q = q0 + w*16 + lg*4 + r) ----
#pragma unroll
        for (int r = 0; r < 4; ++r) {
            float lst = __shfl(ls, lg * 4 + r, 64);
            float inv = 1.0f / lst;
            int q = q0 + w * 16 + lg * 4 + r;
            unsigned short* yrow = y + (size_t)(b * T_ + q) * C_ + h * D_;
#pragma unroll
            for (int dt = 0; dt < 4; ++dt)
                yrow[dt * 16 + lr] = f2bf(o[dt][r] * inv);
        }
    }
#undef STAGE
#undef COMPUTE
}

extern "C" void kernel_launch(void* const* d_in, const int* in_sizes, int n_in,
                              void* d_out, int out_size, void* d_ws, size_t ws_size,
                              hipStream_t stream) {
    const float* x  = (const float*)d_in[0];
    const float* Wa = (const float*)d_in[1];
    const float* ba = (const float*)d_in[2];
    const float* Wp = (const float*)d_in[3];
    const float* bp = (const float*)d_in[4];
    float* out = (float*)d_out;

    char* ws = (char*)d_ws;
    unsigned short* xb  = (unsigned short*)(ws);                       // 16 MB
    unsigned short* wat = (unsigned short*)(ws + 16777216);            // 6 MB
    unsigned short* wpt = (unsigned short*)(ws + 23068672);            // 2 MB
    unsigned short* qkv = (unsigned short*)(ws + 25165824);            // 48 MB
    unsigned short* vt  = (unsigned short*)(ws + 75497472);            // 16 MB
    unsigned short* y   = xb;  // xb dead after GEMM1; reuse for attention output

    // x -> bf16
    k_cvt_bf16<<<8192, 256, 0, stream>>>(x, xb, (B_ * T_ * C_) / 4);
    // weights -> bf16 transposed
    k_wtrans<<<dim3(C3_ / 32, C_ / 32), dim3(32, 8), 0, stream>>>(Wa, wat, C_, C3_);
    k_wtrans<<<dim3(C_ / 32, C_ / 32), dim3(32, 8), 0, stream>>>(Wp, wpt, C_, C_);
    // qkv = x @ W_attn + b_attn   (bf16 out)
    k_gemm_bt<true><<<dim3(C3_ / 128, (B_ * T_) / 128), 256, 0, stream>>>(
        xb, wat, ba, qkv, nullptr, B_ * T_, C3_, C_);
    // v -> vt[bh][d][t]
    k_prep_vt<<<dim3(T_ / 64, B_ * H_), 256, 0, stream>>>(qkv, vt);
    // attention
    k_attn<<<1024, 256, 0, stream>>>(qkv, vt, y);
    // out = y @ W_proj + b_proj   (fp32 out)
    k_gemm_bt<false><<<dim3(C_ / 128, (B_ * T_) / 128), 256, 0, stream>>>(
        y, wpt, bp, nullptr, out, B_ * T_, C_, C_);
}

// Round 6
// 173.158 us; speedup vs baseline: 3.4886x; 1.1422x over previous
//
#include <hip/hip_runtime.h>
#include <stdint.h>

typedef __attribute__((ext_vector_type(8))) short short8;
typedef __attribute__((ext_vector_type(4))) short short4v;
typedef __attribute__((ext_vector_type(4))) float f32x4;
typedef __attribute__((ext_vector_type(2))) unsigned int uint2v;

#define B_ 4
#define T_ 2048
#define C_ 1024
#define H_ 16
#define D_ 64
#define C3_ 3072

#define AS1 __attribute__((address_space(1)))
#define AS3 __attribute__((address_space(3)))

#define QK_SCALE 0.18033688f   /* 1/sqrt(64) * log2(e), folded into Q at GEMM1 epilogue */

__device__ __forceinline__ unsigned short f2bf(float f) {
    union { float f; uint32_t u; } v; v.f = f;
    uint32_t r = v.u + 0x7FFFu + ((v.u >> 16) & 1u);
    return (unsigned short)(r >> 16);
}

__device__ __forceinline__ uint32_t pk_bf16(float lo, float hi) {
    uint32_t r;
    asm("v_cvt_pk_bf16_f32 %0, %1, %2" : "=v"(r) : "v"(lo), "v"(hi));
    return r;
}

// ---------------- fp32 -> bf16 elementwise ----------------
__global__ void k_cvt_bf16(const float* __restrict__ in, unsigned short* __restrict__ out, int n4) {
    int i = blockIdx.x * blockDim.x + threadIdx.x;
    if (i >= n4) return;
    float4 v = ((const float4*)in)[i];
    unsigned short o0 = f2bf(v.x), o1 = f2bf(v.y), o2 = f2bf(v.z), o3 = f2bf(v.w);
    unsigned long long packed = (unsigned long long)o0 | ((unsigned long long)o1 << 16)
        | ((unsigned long long)o2 << 32) | ((unsigned long long)o3 << 48);
    *(unsigned long long*)(out + (size_t)i * 4) = packed;
}

// ---------------- W[K][N] fp32 -> WT[N][K] bf16 ----------------
__global__ void k_wtrans(const float* __restrict__ W, unsigned short* __restrict__ WT, int K, int N) {
    __shared__ float t[32][33];
    int n0 = blockIdx.x * 32, k0 = blockIdx.y * 32;
    int tx = threadIdx.x, ty = threadIdx.y; // (32,8)
#pragma unroll
    for (int i = 0; i < 4; ++i)
        t[ty + i * 8][tx] = W[(size_t)(k0 + ty + i * 8) * N + n0 + tx];
    __syncthreads();
#pragma unroll
    for (int i = 0; i < 4; ++i)
        WT[(size_t)(n0 + ty + i * 8) * K + k0 + tx] = f2bf(t[tx][ty + i * 8]);
}

// ---------------- extract V head-major transposed: vt[bh][d][t] ----------------
__global__ void k_prep_vt(const unsigned short* __restrict__ qkv, unsigned short* __restrict__ vt) {
    int bh = blockIdx.y; int b = bh >> 4, h = bh & 15;
    int t0 = blockIdx.x * 64;
    __shared__ unsigned short tile[64][72];
    int tid = threadIdx.x;
    int r = tid >> 3;          // 0..31
    int c = (tid & 7) * 8;     // 0..56
#pragma unroll
    for (int rr = 0; rr < 64; rr += 32) {
        const unsigned short* src = qkv + (size_t)(b * T_ + t0 + r + rr) * C3_ + 2 * C_ + h * D_ + c;
        short8 v = *(const short8*)src;
#pragma unroll
        for (int j = 0; j < 8; ++j) tile[r + rr][c + j] = (unsigned short)v[j];
    }
    __syncthreads();
#pragma unroll
    for (int rr = 0; rr < 64; rr += 32) {
        int d = r + rr;
        short8 sv;
#pragma unroll
        for (int j = 0; j < 8; ++j) sv[j] = (short)tile[c + j][d];
        *(short8*)(vt + (size_t)bh * D_ * T_ + (size_t)d * T_ + t0 + c) = sv;
    }
}

// ---------------- GEMM: C[M][N] = A[M][K](bf16) @ BT[N][K](bf16)^T + bias ----------------
// OUT_BF16 path additionally scales columns [0,1024) by QK_SCALE (Q pre-scaling for attention).
template<bool OUT_BF16>
__global__ __launch_bounds__(256) void k_gemm_bt(const unsigned short* __restrict__ A,
                                                 const unsigned short* __restrict__ BT,
                                                 const float* __restrict__ bias,
                                                 unsigned short* __restrict__ outb,
                                                 float* __restrict__ outf,
                                                 int M, int N, int K) {
    __shared__ unsigned short a_lds[2][128 * 32];
    __shared__ unsigned short b_lds[2][128 * 32];
    int tid = threadIdx.x;
    int w = tid >> 6, lane = tid & 63;
    int wr = w >> 1, wc = w & 1;
    int m0 = blockIdx.y * 128, n0 = blockIdx.x * 128;
    int lr = lane & 15, lg = lane >> 4;

    f32x4 acc[4][4] = {};

#define STAGE(buf, kt)                                                                              \
    {                                                                                               \
        _Pragma("unroll")                                                                           \
        for (int i = 0; i < 2; ++i) {                                                               \
            int g = i * 256 + tid;                                                                  \
            int row = g >> 2, kc = g & 3;                                                           \
            const unsigned short* srcA = A + (size_t)(m0 + row) * K + (kt) * 32 + kc * 8;           \
            const unsigned short* srcB = BT + (size_t)(n0 + row) * K + (kt) * 32 + kc * 8;          \
            unsigned short* dA = &a_lds[buf][(i * 256 + w * 64) * 8];                               \
            unsigned short* dB = &b_lds[buf][(i * 256 + w * 64) * 8];                               \
            __builtin_amdgcn_global_load_lds((const AS1 void*)srcA,                                 \
                                             (AS3 void*)dA, 16, 0, 0);                              \
            __builtin_amdgcn_global_load_lds((const AS1 void*)srcB,                                 \
                                             (AS3 void*)dB, 16, 0, 0);                              \
        }                                                                                           \
    }

    int NT = K >> 5;
    STAGE(0, 0);
    asm volatile("s_waitcnt vmcnt(0)" ::: "memory");
    __syncthreads();
    int cur = 0;
    for (int kt = 0; kt < NT; ++kt) {
        if (kt + 1 < NT) STAGE(cur ^ 1, kt + 1);
        int koff = lg * 8;
        short8 a[4], b[4];
#pragma unroll
        for (int i = 0; i < 4; ++i)
            a[i] = *(const short8*)&a_lds[cur][(wr * 64 + i * 16 + lr) * 32 + koff];
#pragma unroll
        for (int j = 0; j < 4; ++j)
            b[j] = *(const short8*)&b_lds[cur][(wc * 64 + j * 16 + lr) * 32 + koff];
#pragma unroll
        for (int i = 0; i < 4; ++i)
#pragma unroll
            for (int j = 0; j < 4; ++j)
                acc[i][j] = __builtin_amdgcn_mfma_f32_16x16x32_bf16(a[i], b[j], acc[i][j], 0, 0, 0);
        asm volatile("s_waitcnt vmcnt(0)" ::: "memory");
        __syncthreads();
        cur ^= 1;
    }
#undef STAGE

#pragma unroll
    for (int i = 0; i < 4; ++i) {
        int row = m0 + wr * 64 + i * 16 + lg * 4;
#pragma unroll
        for (int j = 0; j < 4; ++j) {
            int col = n0 + wc * 64 + j * 16 + lr;
            float bv = bias[col];
#pragma unroll
            for (int r = 0; r < 4; ++r) {
                float v = acc[i][j][r] + bv;
                if (OUT_BF16) {
                    if (col < C_) v *= QK_SCALE;   // pre-scale Q columns
                    outb[(size_t)(row + r) * N + col] = f2bf(v);
                } else {
                    outf[(size_t)(row + r) * N + col] = v;
                }
            }
        }
    }
}

// ---------------- causal flash attention (swapped QK^T, no-max softmax) ----------------
// LDS arena layout (bytes):
//   [0,8192)      K buf0      [8192,16384)   K buf1
//   [16384,24576) V buf0      [24576,32768)  V buf1
//   [32768,40960) P per-wave (w*2048), conflict-free half-parity swizzle
__global__ __launch_bounds__(256, 4) void k_attn(const unsigned short* __restrict__ qkv,
                                                 const unsigned short* __restrict__ vt,
                                                 unsigned short* __restrict__ y) {
    __shared__ char arena[40960];
    int tid = threadIdx.x;
    int w = tid >> 6, lane = tid & 63;
    int lr = lane & 15, lg = lane >> 4;

    // bijective XCD-chunk swizzle (1024 % 8 == 0)
    int bid = blockIdx.x;
    int bid2 = (bid & 7) * 128 + (bid >> 3);
    int bh = bid2 >> 4, pair = bid2 & 15;
    int b = bh >> 4, h = bh & 15;

    const unsigned short* kbase = qkv + (size_t)(b * T_) * C3_ + C_ + h * D_;
    const unsigned short* vtb = vt + (size_t)bh * D_ * T_;

    // --- precomputed LDS addresses (tile-invariant) ---
    int sw_ = (lr & 7) << 4;
    int RB0 = lr * 128 + ((lg * 16) ^ sw_);   // K/V frag base (imm: arrayoff + buf + j*2048)
    int RB1 = RB0 ^ 64;
    int jl = (lr >> 1) & 3;
    int pbase = 32768 + w * 2048 + lr * 128
              + ((((lg >> 1) ^ (lr & 1)) << 4) | (((lg & 1) ^ (lr >> 3)) << 3));
    int pwa[4];
#pragma unroll
    for (int j = 0; j < 4; ++j) pwa[j] = pbase + ((j ^ jl) << 5);
    // P A-frag read addresses: XOR for the 64-offset (bit 6 lives inside the
    // swizzled column field — ADDITION WOULD CARRY into the row bits), plus
    // half-swap (+8, never carries: bit 3 of prd0 is 0) baked into the address.
    int prd0 = 32768 + w * 2048 + lr * 128 + ((lg ^ (lr & 7)) << 4);
    int prd1 = prd0 ^ 64;
    int hs = lr & 8;
    int prA0a = prd0 + hs,       prA0b = prd0 + (8 ^ hs);
    int prA1a = prd1 + hs,       prA1b = prd1 + (8 ^ hs);

    // --- global stage sources (loop-carried pointers) ---
    int row0 = tid >> 3, row1 = 32 + (tid >> 3);
    int scol0 = ((tid & 7) << 4) ^ ((row0 & 7) << 4);
    int scol1 = ((tid & 7) << 4) ^ ((row1 & 7) << 4);

    const char *sK0, *sK1, *sV0, *sV1;

#define STAGE(LDSOFF)                                                                                   \
    {                                                                                                   \
        __builtin_amdgcn_global_load_lds((const AS1 void*)sK0, (AS3 void*)(arena + (LDSOFF) + w * 1024), 16, 0, 0);          \
        __builtin_amdgcn_global_load_lds((const AS1 void*)sK1, (AS3 void*)(arena + (LDSOFF) + 4096 + w * 1024), 16, 0, 0);   \
        __builtin_amdgcn_global_load_lds((const AS1 void*)sV0, (AS3 void*)(arena + 16384 + (LDSOFF) + w * 1024), 16, 0, 0);  \
        __builtin_amdgcn_global_load_lds((const AS1 void*)sV1, (AS3 void*)(arena + 16384 + (LDSOFF) + 4096 + w * 1024), 16, 0, 0); \
        sK0 += 64 * C3_ * 2; sK1 += 64 * C3_ * 2; sV0 += 128; sV1 += 128;                               \
    }

#define COMPUTE(LDSOFF, KT)                                                                             \
    {                                                                                                   \
        f32x4 s[4];                                                                                     \
        __builtin_amdgcn_s_setprio(1);                                                                  \
        _Pragma("unroll")                                                                               \
        for (int j = 0; j < 4; ++j) {                                                                   \
            short8 kf0 = *(const short8*)(arena + RB0 + (LDSOFF) + j * 2048);                           \
            short8 kf1 = *(const short8*)(arena + RB1 + (LDSOFF) + j * 2048);                           \
            f32x4 z = {};                                                                               \
            z = __builtin_amdgcn_mfma_f32_16x16x32_bf16(kf0, qf0, z, 0, 0, 0);                          \
            s[j] = __builtin_amdgcn_mfma_f32_16x16x32_bf16(kf1, qf1, z, 0, 0, 0);                       \
        }                                                                                               \
        __builtin_amdgcn_s_setprio(0);                                                                  \
        if ((KT) == ntiles - 1) {                                                                       \
            int kb = (KT) * 64 + lg * 4 - qv;                                                           \
            _Pragma("unroll")                                                                           \
            for (int j = 0; j < 4; ++j)                                                                 \
                _Pragma("unroll")                                                                       \
                for (int r = 0; r < 4; ++r)                                                             \
                    if (kb + j * 16 + r > 0) s[j][r] = -INFINITY;                                       \
        }                                                                                               \
        _Pragma("unroll")                                                                               \
        for (int j = 0; j < 4; ++j)                                                                     \
            _Pragma("unroll")                                                                           \
            for (int r = 0; r < 4; ++r) {                                                               \
                float pv = __builtin_amdgcn_exp2f(s[j][r]);                                             \
                s[j][r] = pv;                                                                           \
                ls += pv;                                                                               \
            }                                                                                           \
        _Pragma("unroll")                                                                               \
        for (int j = 0; j < 4; ++j) {                                                                   \
            uint2v W;                                                                                   \
            W[0] = pk_bf16(s[j][0], s[j][1]);                                                           \
            W[1] = pk_bf16(s[j][2], s[j][3]);                                                           \
            *(uint2v*)(arena + pwa[j]) = W;                                                             \
        }                                                                                               \
        short4v l0 = *(const short4v*)(arena + prA0a);                                                  \
        short4v h0 = *(const short4v*)(arena + prA0b);                                                  \
        short4v l1 = *(const short4v*)(arena + prA1a);                                                  \
        short4v h1 = *(const short4v*)(arena + prA1b);                                                  \
        short8 pa0 = __builtin_shufflevector(l0, h0, 0, 1, 2, 3, 4, 5, 6, 7);                           \
        short8 pa1 = __builtin_shufflevector(l1, h1, 0, 1, 2, 3, 4, 5, 6, 7);                           \
        __builtin_amdgcn_s_setprio(1);                                                                  \
        _Pragma("unroll")                                                                               \
        for (int dt = 0; dt < 4; ++dt) {                                                                \
            short8 vf0 = *(const short8*)(arena + RB0 + 16384 + (LDSOFF) + dt * 2048);                  \
            short8 vf1 = *(const short8*)(arena + RB1 + 16384 + (LDSOFF) + dt * 2048);                  \
            o[dt] = __builtin_amdgcn_mfma_f32_16x16x32_bf16(pa0, vf0, o[dt], 0, 0, 0);                  \
            o[dt] = __builtin_amdgcn_mfma_f32_16x16x32_bf16(pa1, vf1, o[dt], 0, 0, 0);                  \
        }                                                                                               \
        __builtin_amdgcn_s_setprio(0);                                                                  \
    }

#pragma unroll 1
    for (int half = 0; half < 2; ++half) {
        int qt = half ? (31 - pair) : pair;
        int q0 = qt * 64;
        int ntiles = qt + 1;

        const unsigned short* qrow = qkv + (size_t)(b * T_ + q0 + w * 16 + lr) * C3_ + h * D_;
        short8 qf0 = *(const short8*)(qrow + lg * 8);
        short8 qf1 = *(const short8*)(qrow + 32 + lg * 8);

        f32x4 o[4] = {};
        float ls = 0.f;    // in-lane partial of unnormalized row-sum (q = q0 + w*16 + lr)
        int qv = q0 + w * 16 + lr;

        sK0 = (const char*)(kbase + (size_t)row0 * C3_) + scol0;
        sK1 = (const char*)(kbase + (size_t)row1 * C3_) + scol1;
        sV0 = (const char*)(vtb + (size_t)row0 * T_) + scol0;
        sV1 = (const char*)(vtb + (size_t)row1 * T_) + scol1;

        STAGE(0);
        asm volatile("s_waitcnt vmcnt(0)" ::: "memory");
        __syncthreads();

#pragma unroll 1
        for (int kt = 0; kt < ntiles; kt += 2) {
            if (kt + 1 < ntiles) STAGE(8192);
            COMPUTE(0, kt);
            asm volatile("s_waitcnt vmcnt(0)" ::: "memory");
            __syncthreads();
            if (kt + 1 < ntiles) {
                if (kt + 2 < ntiles) STAGE(0);
                COMPUTE(8192, kt + 1);
                asm volatile("s_waitcnt vmcnt(0)" ::: "memory");
                __syncthreads();
            }
        }

        // ---- combine lg-partials of ls, normalize + store ----
        ls += __shfl_xor(ls, 16);
        ls += __shfl_xor(ls, 32);
#pragma unroll
        for (int r = 0; r < 4; ++r) {
            float lst = __shfl(ls, lg * 4 + r, 64);
            float inv = 1.0f / lst;
            int q = q0 + w * 16 + lg * 4 + r;
            unsigned short* yrow = y + (size_t)(b * T_ + q) * C_ + h * D_;
#pragma unroll
            for (int dt = 0; dt < 4; ++dt)
                yrow[dt * 16 + lr] = f2bf(o[dt][r] * inv);
        }
    }
#undef STAGE
#undef COMPUTE
}

extern "C" void kernel_launch(void* const* d_in, const int* in_sizes, int n_in,
                              void* d_out, int out_size, void* d_ws, size_t ws_size,
                              hipStream_t stream) {
    const float* x  = (const float*)d_in[0];
    const float* Wa = (const float*)d_in[1];
    const float* ba = (const float*)d_in[2];
    const float* Wp = (const float*)d_in[3];
    const float* bp = (const float*)d_in[4];
    float* out = (float*)d_out;

    char* ws = (char*)d_ws;
    unsigned short* xb  = (unsigned short*)(ws);                       // 16 MB
    unsigned short* wat = (unsigned short*)(ws + 16777216);            // 6 MB
    unsigned short* wpt = (unsigned short*)(ws + 23068672);            // 2 MB
    unsigned short* qkv = (unsigned short*)(ws + 25165824);            // 48 MB
    unsigned short* vt  = (unsigned short*)(ws + 75497472);            // 16 MB
    unsigned short* y   = xb;  // xb dead after GEMM1; reuse for attention output

    // x -> bf16
    k_cvt_bf16<<<8192, 256, 0, stream>>>(x, xb, (B_ * T_ * C_) / 4);
    // weights -> bf16 transposed
    k_wtrans<<<dim3(C3_ / 32, C_ / 32), dim3(32, 8), 0, stream>>>(Wa, wat, C_, C3_);
    k_wtrans<<<dim3(C_ / 32, C_ / 32), dim3(32, 8), 0, stream>>>(Wp, wpt, C_, C_);
    // qkv = x @ W_attn + b_attn   (bf16 out, Q pre-scaled)
    k_gemm_bt<true><<<dim3(C3_ / 128, (B_ * T_) / 128), 256, 0, stream>>>(
        xb, wat, ba, qkv, nullptr, B_ * T_, C3_, C_);
    // v -> vt[bh][d][t]
    k_prep_vt<<<dim3(T_ / 64, B_ * H_), 256, 0, stream>>>(qkv, vt);
    // attention
    k_attn<<<1024, 256, 0, stream>>>(qkv, vt, y);
    // out = y @ W_proj + b_proj   (fp32 out)
    k_gemm_bt<false><<<dim3(C_ / 128, (B_ * T_) / 128), 256, 0, stream>>>(
        y, wpt, bp, nullptr, out, B_ * T_, C_, C_);
}

// Round 8
// 168.019 us; speedup vs baseline: 3.5953x; 1.0306x over previous
//
#include <hip/hip_runtime.h>
#include <stdint.h>

typedef __attribute__((ext_vector_type(8))) short short8;
typedef __attribute__((ext_vector_type(4))) short short4v;
typedef __attribute__((ext_vector_type(4))) float f32x4;
typedef __attribute__((ext_vector_type(2))) unsigned int uint2v;

#define B_ 4
#define T_ 2048
#define C_ 1024
#define H_ 16
#define D_ 64
#define C3_ 3072

#define AS1 __attribute__((address_space(1)))
#define AS3 __attribute__((address_space(3)))

#define QK_SCALE 0.18033688f   /* 1/sqrt(64) * log2(e), folded into Q at GEMM1 epilogue */

__device__ __forceinline__ unsigned short f2bf(float f) {
    union { float f; uint32_t u; } v; v.f = f;
    uint32_t r = v.u + 0x7FFFu + ((v.u >> 16) & 1u);
    return (unsigned short)(r >> 16);
}

__device__ __forceinline__ uint32_t pk_bf16(float lo, float hi) {
    uint32_t r;
    asm("v_cvt_pk_bf16_f32 %0, %1, %2" : "=v"(r) : "v"(lo), "v"(hi));
    return r;
}

// ---------------- fp32 -> bf16 elementwise ----------------
__global__ void k_cvt_bf16(const float* __restrict__ in, unsigned short* __restrict__ out, int n4) {
    int i = blockIdx.x * blockDim.x + threadIdx.x;
    if (i >= n4) return;
    float4 v = ((const float4*)in)[i];
    unsigned short o0 = f2bf(v.x), o1 = f2bf(v.y), o2 = f2bf(v.z), o3 = f2bf(v.w);
    unsigned long long packed = (unsigned long long)o0 | ((unsigned long long)o1 << 16)
        | ((unsigned long long)o2 << 32) | ((unsigned long long)o3 << 48);
    *(unsigned long long*)(out + (size_t)i * 4) = packed;
}

// ---------------- W[K][N] fp32 -> WT[N][K] bf16 ----------------
__global__ void k_wtrans(const float* __restrict__ W, unsigned short* __restrict__ WT, int K, int N) {
    __shared__ float t[32][33];
    int n0 = blockIdx.x * 32, k0 = blockIdx.y * 32;
    int tx = threadIdx.x, ty = threadIdx.y; // (32,8)
#pragma unroll
    for (int i = 0; i < 4; ++i)
        t[ty + i * 8][tx] = W[(size_t)(k0 + ty + i * 8) * N + n0 + tx];
    __syncthreads();
#pragma unroll
    for (int i = 0; i < 4; ++i)
        WT[(size_t)(n0 + ty + i * 8) * K + k0 + tx] = f2bf(t[tx][ty + i * 8]);
}

// ---------------- extract V head-major transposed: vt[bh][d][t] ----------------
__global__ void k_prep_vt(const unsigned short* __restrict__ qkv, unsigned short* __restrict__ vt) {
    int bh = blockIdx.y; int b = bh >> 4, h = bh & 15;
    int t0 = blockIdx.x * 64;
    __shared__ unsigned short tile[64][72];
    int tid = threadIdx.x;
    int r = tid >> 3;          // 0..31
    int c = (tid & 7) * 8;     // 0..56
#pragma unroll
    for (int rr = 0; rr < 64; rr += 32) {
        const unsigned short* src = qkv + (size_t)(b * T_ + t0 + r + rr) * C3_ + 2 * C_ + h * D_ + c;
        short8 v = *(const short8*)src;
#pragma unroll
        for (int j = 0; j < 8; ++j) tile[r + rr][c + j] = (unsigned short)v[j];
    }
    __syncthreads();
#pragma unroll
    for (int rr = 0; rr < 64; rr += 32) {
        int d = r + rr;
        short8 sv;
#pragma unroll
        for (int j = 0; j < 8; ++j) sv[j] = (short)tile[c + j][d];
        *(short8*)(vt + (size_t)bh * D_ * T_ + (size_t)d * T_ + t0 + c) = sv;
    }
}

// ---------------- GEMM: C[M][N] = A[M][K](bf16) @ BT[N][K](bf16)^T + bias ----------------
// BM=256, BN=128, BK=64, 512 threads (8 waves: 4 M-rows x 2 N-cols).
// 3-deep LDS pipeline, counted vmcnt(6), raw s_barrier (no implicit drain).
// LDS per buffer: A 256x64 bf16 (32KB) + B 128x64 bf16 (16KB) = 48KB; x3 = 144KB.
// Swizzle: byte ^= ((row&7)<<4), applied via pre-swizzled global source (linear LDS dest).
// OUT_BF16 path additionally scales columns [0,1024) by QK_SCALE (Q pre-scaling).
template<bool OUT_BF16>
__global__ __launch_bounds__(512) void k_gemm_bt(const unsigned short* __restrict__ A,
                                                 const unsigned short* __restrict__ BT,
                                                 const float* __restrict__ bias,
                                                 unsigned short* __restrict__ outb,
                                                 float* __restrict__ outf,
                                                 int M, int N, int K) {
    __shared__ __align__(16) char arena[147456];
    int tid = threadIdx.x;
    int w = tid >> 6, lane = tid & 63;
    int wrow = w >> 1, wcol = w & 1;
    int m0 = blockIdx.y * 256, n0 = blockIdx.x * 128;
    int lr = lane & 15, lg = lane >> 4;

    f32x4 acc[4][4] = {};

    // --- staging source pointers (pre-swizzled global col; linear LDS dest) ---
    int gr = tid >> 3;                      // base row 0..63
    int scb = ((tid & 7) << 4) ^ (((tid >> 3) & 7) << 4);
    const char* sA[4];
    const char* sB[2];
#pragma unroll
    for (int r = 0; r < 4; ++r)
        sA[r] = (const char*)A + (size_t)(m0 + gr + r * 64) * K * 2 + scb;
#pragma unroll
    for (int r = 0; r < 2; ++r)
        sB[r] = (const char*)BT + (size_t)(n0 + gr + r * 64) * K * 2 + scb;

    // --- ds_read fragment addresses (tile-invariant; +OFS at use) ---
    int inner = (lg * 16) ^ ((lr & 7) << 4);
    int aoff = wrow * 8192 + lr * 128 + inner;            // A frag base
    int boff = 32768 + wcol * 8192 + lr * 128 + inner;    // B frag base

#define GSTAGE(OFS)                                                                                 \
    {                                                                                               \
        _Pragma("unroll")                                                                           \
        for (int r = 0; r < 4; ++r) {                                                               \
            __builtin_amdgcn_global_load_lds((const AS1 void*)sA[r],                                \
                (AS3 void*)(arena + (OFS) + tid * 16 + r * 8192), 16, 0, 0);                        \
            sA[r] += 128;                                                                           \
        }                                                                                           \
        _Pragma("unroll")                                                                           \
        for (int r = 0; r < 2; ++r) {                                                               \
            __builtin_amdgcn_global_load_lds((const AS1 void*)sB[r],                                \
                (AS3 void*)(arena + (OFS) + 32768 + tid * 16 + r * 8192), 16, 0, 0);                \
            sB[r] += 128;                                                                           \
        }                                                                                           \
    }

#define GCOMPUTE(OFS)                                                                               \
    {                                                                                               \
        short8 af[4][2], bf[4][2];                                                                  \
        _Pragma("unroll")                                                                           \
        for (int i = 0; i < 4; ++i) {                                                               \
            int addrA = (OFS) + aoff + i * 2048;                                                    \
            af[i][0] = *(const short8*)(arena + addrA);                                             \
            af[i][1] = *(const short8*)(arena + (addrA ^ 64));                                      \
        }                                                                                           \
        _Pragma("unroll")                                                                           \
        for (int j = 0; j < 4; ++j) {                                                               \
            int addrB = (OFS) + boff + j * 2048;                                                    \
            bf[j][0] = *(const short8*)(arena + addrB);                                             \
            bf[j][1] = *(const short8*)(arena + (addrB ^ 64));                                      \
        }                                                                                           \
        __builtin_amdgcn_s_setprio(1);                                                              \
        _Pragma("unroll")                                                                           \
        for (int i = 0; i < 4; ++i)                                                                 \
            _Pragma("unroll")                                                                       \
            for (int j = 0; j < 4; ++j) {                                                           \
                acc[i][j] = __builtin_amdgcn_mfma_f32_16x16x32_bf16(af[i][0], bf[j][0], acc[i][j], 0, 0, 0); \
                acc[i][j] = __builtin_amdgcn_mfma_f32_16x16x32_bf16(af[i][1], bf[j][1], acc[i][j], 0, 0, 0); \
            }                                                                                       \
        __builtin_amdgcn_s_setprio(0);                                                              \
    }

    int NT = K >> 6;   // K / 64
    int ofs0 = 0, ofs1 = 49152, ofs2 = 98304;

    GSTAGE(ofs0);
    GSTAGE(ofs1);
    asm volatile("s_waitcnt vmcnt(6)" ::: "memory");   // tile 0 complete (tile 1 in flight)
    __builtin_amdgcn_s_barrier();
    __builtin_amdgcn_sched_barrier(0);

    for (int t = 0; t < NT; ++t) {
        bool pf = (t + 2 < NT);
        if (pf) GSTAGE(ofs2);
        GCOMPUTE(ofs0);
        if (pf) { asm volatile("s_waitcnt vmcnt(6)" ::: "memory"); }
        else    { asm volatile("s_waitcnt vmcnt(0)" ::: "memory"); }
        __builtin_amdgcn_s_barrier();
        __builtin_amdgcn_sched_barrier(0);
        int tmp = ofs0; ofs0 = ofs1; ofs1 = ofs2; ofs2 = tmp;
    }
#undef GSTAGE
#undef GCOMPUTE

    // ---- epilogue ----
#pragma unroll
    for (int i = 0; i < 4; ++i) {
        int row = m0 + wrow * 64 + i * 16 + lg * 4;
#pragma unroll
        for (int j = 0; j < 4; ++j) {
            int col = n0 + wcol * 64 + j * 16 + lr;
            float bv = bias[col];
#pragma unroll
            for (int r = 0; r < 4; ++r) {
                float v = acc[i][j][r] + bv;
                if (OUT_BF16) {
                    if (col < C_) v *= QK_SCALE;   // pre-scale Q columns
                    outb[(size_t)(row + r) * N + col] = f2bf(v);
                } else {
                    outf[(size_t)(row + r) * N + col] = v;
                }
            }
        }
    }
}

// ---------------- causal flash attention (swapped QK^T, no-max softmax) ----------------
// LDS arena layout (bytes):
//   [0,8192)      K buf0      [8192,16384)   K buf1
//   [16384,24576) V buf0      [24576,32768)  V buf1
//   [32768,40960) P per-wave (w*2048), conflict-free half-parity swizzle
__global__ __launch_bounds__(256, 4) void k_attn(const unsigned short* __restrict__ qkv,
                                                 const unsigned short* __restrict__ vt,
                                                 unsigned short* __restrict__ y) {
    __shared__ __align__(16) char arena[40960];
    int tid = threadIdx.x;
    int w = tid >> 6, lane = tid & 63;
    int lr = lane & 15, lg = lane >> 4;

    // bijective XCD-chunk swizzle (1024 % 8 == 0)
    int bid = blockIdx.x;
    int bid2 = (bid & 7) * 128 + (bid >> 3);
    int bh = bid2 >> 4, pair = bid2 & 15;
    int b = bh >> 4, h = bh & 15;

    const unsigned short* kbase = qkv + (size_t)(b * T_) * C3_ + C_ + h * D_;
    const unsigned short* vtb = vt + (size_t)bh * D_ * T_;

    // --- precomputed LDS addresses (tile-invariant) ---
    int sw_ = (lr & 7) << 4;
    int RB0 = lr * 128 + ((lg * 16) ^ sw_);   // K/V frag base (imm: arrayoff + buf + j*2048)
    int RB1 = RB0 ^ 64;
    int jl = (lr >> 1) & 3;
    int pbase = 32768 + w * 2048 + lr * 128
              + ((((lg >> 1) ^ (lr & 1)) << 4) | (((lg & 1) ^ (lr >> 3)) << 3));
    int pwa[4];
#pragma unroll
    for (int j = 0; j < 4; ++j) pwa[j] = pbase + ((j ^ jl) << 5);
    // P A-frag read addresses: XOR for the 64-offset (bit 6 lives inside the
    // swizzled column field — ADDITION WOULD CARRY into the row bits), plus
    // half-swap (+8, never carries: bit 3 of prd0 is 0) baked into the address.
    int prd0 = 32768 + w * 2048 + lr * 128 + ((lg ^ (lr & 7)) << 4);
    int prd1 = prd0 ^ 64;
    int hs = lr & 8;
    int prA0a = prd0 + hs,       prA0b = prd0 + (8 ^ hs);
    int prA1a = prd1 + hs,       prA1b = prd1 + (8 ^ hs);

    // --- global stage sources (loop-carried pointers) ---
    int row0 = tid >> 3, row1 = 32 + (tid >> 3);
    int scol0 = ((tid & 7) << 4) ^ ((row0 & 7) << 4);
    int scol1 = ((tid & 7) << 4) ^ ((row1 & 7) << 4);

    const char *sK0, *sK1, *sV0, *sV1;

#define ASTAGE(LDSOFF)                                                                                  \
    {                                                                                                   \
        __builtin_amdgcn_global_load_lds((const AS1 void*)sK0, (AS3 void*)(arena + (LDSOFF) + w * 1024), 16, 0, 0);          \
        __builtin_amdgcn_global_load_lds((const AS1 void*)sK1, (AS3 void*)(arena + (LDSOFF) + 4096 + w * 1024), 16, 0, 0);   \
        __builtin_amdgcn_global_load_lds((const AS1 void*)sV0, (AS3 void*)(arena + 16384 + (LDSOFF) + w * 1024), 16, 0, 0);  \
        __builtin_amdgcn_global_load_lds((const AS1 void*)sV1, (AS3 void*)(arena + 16384 + (LDSOFF) + 4096 + w * 1024), 16, 0, 0); \
        sK0 += 64 * C3_ * 2; sK1 += 64 * C3_ * 2; sV0 += 128; sV1 += 128;                               \
    }

#define ACOMPUTE(LDSOFF, KT)                                                                            \
    {                                                                                                   \
        f32x4 s[4];                                                                                     \
        __builtin_amdgcn_s_setprio(1);                                                                  \
        _Pragma("unroll")                                                                               \
        for (int j = 0; j < 4; ++j) {                                                                   \
            short8 kf0 = *(const short8*)(arena + RB0 + (LDSOFF) + j * 2048);                           \
            short8 kf1 = *(const short8*)(arena + RB1 + (LDSOFF) + j * 2048);                           \
            f32x4 z = {};                                                                               \
            z = __builtin_amdgcn_mfma_f32_16x16x32_bf16(kf0, qf0, z, 0, 0, 0);                          \
            s[j] = __builtin_amdgcn_mfma_f32_16x16x32_bf16(kf1, qf1, z, 0, 0, 0);                       \
        }                                                                                               \
        __builtin_amdgcn_s_setprio(0);                                                                  \
        if ((KT) == ntiles - 1) {                                                                       \
            int kb = (KT) * 64 + lg * 4 - qv;                                                           \
            _Pragma("unroll")                                                                           \
            for (int j = 0; j < 4; ++j)                                                                 \
                _Pragma("unroll")                                                                       \
                for (int r = 0; r < 4; ++r)                                                             \
                    if (kb + j * 16 + r > 0) s[j][r] = -INFINITY;                                       \
        }                                                                                               \
        _Pragma("unroll")                                                                               \
        for (int j = 0; j < 4; ++j)                                                                     \
            _Pragma("unroll")                                                                           \
            for (int r = 0; r < 4; ++r) {                                                               \
                float pv = __builtin_amdgcn_exp2f(s[j][r]);                                             \
                s[j][r] = pv;                                                                           \
                ls += pv;                                                                               \
            }                                                                                           \
        _Pragma("unroll")                                                                               \
        for (int j = 0; j < 4; ++j) {                                                                   \
            uint2v W;                                                                                   \
            W[0] = pk_bf16(s[j][0], s[j][1]);                                                           \
            W[1] = pk_bf16(s[j][2], s[j][3]);                                                           \
            *(uint2v*)(arena + pwa[j]) = W;                                                             \
        }                                                                                               \
        short4v l0 = *(const short4v*)(arena + prA0a);                                                  \
        short4v h0 = *(const short4v*)(arena + prA0b);                                                  \
        short4v l1 = *(const short4v*)(arena + prA1a);                                                  \
        short4v h1 = *(const short4v*)(arena + prA1b);                                                  \
        short8 pa0 = __builtin_shufflevector(l0, h0, 0, 1, 2, 3, 4, 5, 6, 7);                           \
        short8 pa1 = __builtin_shufflevector(l1, h1, 0, 1, 2, 3, 4, 5, 6, 7);                           \
        __builtin_amdgcn_s_setprio(1);                                                                  \
        _Pragma("unroll")                                                                               \
        for (int dt = 0; dt < 4; ++dt) {                                                                \
            short8 vf0 = *(const short8*)(arena + RB0 + 16384 + (LDSOFF) + dt * 2048);                  \
            short8 vf1 = *(const short8*)(arena + RB1 + 16384 + (LDSOFF) + dt * 2048);                  \
            o[dt] = __builtin_amdgcn_mfma_f32_16x16x32_bf16(pa0, vf0, o[dt], 0, 0, 0);                  \
            o[dt] = __builtin_amdgcn_mfma_f32_16x16x32_bf16(pa1, vf1, o[dt], 0, 0, 0);                  \
        }                                                                                               \
        __builtin_amdgcn_s_setprio(0);                                                                  \
    }

#pragma unroll 1
    for (int half = 0; half < 2; ++half) {
        int qt = half ? (31 - pair) : pair;
        int q0 = qt * 64;
        int ntiles = qt + 1;

        const unsigned short* qrow = qkv + (size_t)(b * T_ + q0 + w * 16 + lr) * C3_ + h * D_;
        short8 qf0 = *(const short8*)(qrow + lg * 8);
        short8 qf1 = *(const short8*)(qrow + 32 + lg * 8);

        f32x4 o[4] = {};
        float ls = 0.f;    // in-lane partial of unnormalized row-sum (q = q0 + w*16 + lr)
        int qv = q0 + w * 16 + lr;

        sK0 = (const char*)(kbase + (size_t)row0 * C3_) + scol0;
        sK1 = (const char*)(kbase + (size_t)row1 * C3_) + scol1;
        sV0 = (const char*)(vtb + (size_t)row0 * T_) + scol0;
        sV1 = (const char*)(vtb + (size_t)row1 * T_) + scol1;

        ASTAGE(0);
        asm volatile("s_waitcnt vmcnt(0)" ::: "memory");
        __syncthreads();

#pragma unroll 1
        for (int kt = 0; kt < ntiles; kt += 2) {
            if (kt + 1 < ntiles) ASTAGE(8192);
            ACOMPUTE(0, kt);
            asm volatile("s_waitcnt vmcnt(0)" ::: "memory");
            __syncthreads();
            if (kt + 1 < ntiles) {
                if (kt + 2 < ntiles) ASTAGE(0);
                ACOMPUTE(8192, kt + 1);
                asm volatile("s_waitcnt vmcnt(0)" ::: "memory");
                __syncthreads();
            }
        }

        // ---- combine lg-partials of ls, normalize + store ----
        ls += __shfl_xor(ls, 16);
        ls += __shfl_xor(ls, 32);
#pragma unroll
        for (int r = 0; r < 4; ++r) {
            float lst = __shfl(ls, lg * 4 + r, 64);
            float inv = 1.0f / lst;
            int q = q0 + w * 16 + lg * 4 + r;
            unsigned short* yrow = y + (size_t)(b * T_ + q) * C_ + h * D_;
#pragma unroll
            for (int dt = 0; dt < 4; ++dt)
                yrow[dt * 16 + lr] = f2bf(o[dt][r] * inv);
        }
    }
#undef ASTAGE
#undef ACOMPUTE
}

extern "C" void kernel_launch(void* const* d_in, const int* in_sizes, int n_in,
                              void* d_out, int out_size, void* d_ws, size_t ws_size,
                              hipStream_t stream) {
    const float* x  = (const float*)d_in[0];
    const float* Wa = (const float*)d_in[1];
    const float* ba = (const float*)d_in[2];
    const float* Wp = (const float*)d_in[3];
    const float* bp = (const float*)d_in[4];
    float* out = (float*)d_out;

    char* ws = (char*)d_ws;
    unsigned short* xb  = (unsigned short*)(ws);                       // 16 MB
    unsigned short* wat = (unsigned short*)(ws + 16777216);            // 6 MB
    unsigned short* wpt = (unsigned short*)(ws + 23068672);            // 2 MB
    unsigned short* qkv = (unsigned short*)(ws + 25165824);            // 48 MB
    unsigned short* vt  = (unsigned short*)(ws + 75497472);            // 16 MB
    unsigned short* y   = xb;  // xb dead after GEMM1; reuse for attention output

    // x -> bf16
    k_cvt_bf16<<<8192, 256, 0, stream>>>(x, xb, (B_ * T_ * C_) / 4);
    // weights -> bf16 transposed
    k_wtrans<<<dim3(C3_ / 32, C_ / 32), dim3(32, 8), 0, stream>>>(Wa, wat, C_, C3_);
    k_wtrans<<<dim3(C_ / 32, C_ / 32), dim3(32, 8), 0, stream>>>(Wp, wpt, C_, C_);
    // qkv = x @ W_attn + b_attn   (bf16 out, Q pre-scaled)
    k_gemm_bt<true><<<dim3(C3_ / 128, (B_ * T_) / 256), 512, 0, stream>>>(
        xb, wat, ba, qkv, nullptr, B_ * T_, C3_, C_);
    // v -> vt[bh][d][t]
    k_prep_vt<<<dim3(T_ / 64, B_ * H_), 256, 0, stream>>>(qkv, vt);
    // attention
    k_attn<<<1024, 256, 0, stream>>>(qkv, vt, y);
    // out = y @ W_proj + b_proj   (fp32 out)
    k_gemm_bt<false><<<dim3(C_ / 128, (B_ * T_) / 256), 512, 0, stream>>>(
        y, wpt, bp, nullptr, out, B_ * T_, C_, C_);
}

// Round 9
// 166.006 us; speedup vs baseline: 3.6389x; 1.0121x over previous
//
#include <hip/hip_runtime.h>
#include <stdint.h>

typedef __attribute__((ext_vector_type(8))) short short8;
typedef __attribute__((ext_vector_type(4))) short short4v;
typedef __attribute__((ext_vector_type(4))) float f32x4;
typedef __attribute__((ext_vector_type(2))) unsigned int uint2v;

#define B_ 4
#define T_ 2048
#define C_ 1024
#define H_ 16
#define D_ 64
#define C3_ 3072

#define AS1 __attribute__((address_space(1)))
#define AS3 __attribute__((address_space(3)))

#define QK_SCALE 0.18033688f   /* 1/sqrt(64) * log2(e), folded into Q at GEMM1 epilogue */

__device__ __forceinline__ unsigned short f2bf(float f) {
    union { float f; uint32_t u; } v; v.f = f;
    uint32_t r = v.u + 0x7FFFu + ((v.u >> 16) & 1u);
    return (unsigned short)(r >> 16);
}

__device__ __forceinline__ uint32_t pk_bf16(float lo, float hi) {
    uint32_t r;
    asm("v_cvt_pk_bf16_f32 %0, %1, %2" : "=v"(r) : "v"(lo), "v"(hi));
    return r;
}

// ---------------- fp32 -> bf16 elementwise ----------------
__global__ void k_cvt_bf16(const float* __restrict__ in, unsigned short* __restrict__ out, int n4) {
    int i = blockIdx.x * blockDim.x + threadIdx.x;
    if (i >= n4) return;
    float4 v = ((const float4*)in)[i];
    unsigned short o0 = f2bf(v.x), o1 = f2bf(v.y), o2 = f2bf(v.z), o3 = f2bf(v.w);
    unsigned long long packed = (unsigned long long)o0 | ((unsigned long long)o1 << 16)
        | ((unsigned long long)o2 << 32) | ((unsigned long long)o3 << 48);
    *(unsigned long long*)(out + (size_t)i * 4) = packed;
}

// ---------------- W[K][N] fp32 -> WT[N][K] bf16 ----------------
__global__ void k_wtrans(const float* __restrict__ W, unsigned short* __restrict__ WT, int K, int N) {
    __shared__ float t[32][33];
    int n0 = blockIdx.x * 32, k0 = blockIdx.y * 32;
    int tx = threadIdx.x, ty = threadIdx.y; // (32,8)
#pragma unroll
    for (int i = 0; i < 4; ++i)
        t[ty + i * 8][tx] = W[(size_t)(k0 + ty + i * 8) * N + n0 + tx];
    __syncthreads();
#pragma unroll
    for (int i = 0; i < 4; ++i)
        WT[(size_t)(n0 + ty + i * 8) * K + k0 + tx] = f2bf(t[tx][ty + i * 8]);
}

// ---------------- extract V head-major transposed: vt[bh][d][t] ----------------
__global__ void k_prep_vt(const unsigned short* __restrict__ qkv, unsigned short* __restrict__ vt) {
    int bh = blockIdx.y; int b = bh >> 4, h = bh & 15;
    int t0 = blockIdx.x * 64;
    __shared__ unsigned short tile[64][72];
    int tid = threadIdx.x;
    int r = tid >> 3;          // 0..31
    int c = (tid & 7) * 8;     // 0..56
#pragma unroll
    for (int rr = 0; rr < 64; rr += 32) {
        const unsigned short* src = qkv + (size_t)(b * T_ + t0 + r + rr) * C3_ + 2 * C_ + h * D_ + c;
        short8 v = *(const short8*)src;
#pragma unroll
        for (int j = 0; j < 8; ++j) tile[r + rr][c + j] = (unsigned short)v[j];
    }
    __syncthreads();
#pragma unroll
    for (int rr = 0; rr < 64; rr += 32) {
        int d = r + rr;
        short8 sv;
#pragma unroll
        for (int j = 0; j < 8; ++j) sv[j] = (short)tile[c + j][d];
        *(short8*)(vt + (size_t)bh * D_ * T_ + (size_t)d * T_ + t0 + c) = sv;
    }
}

// ---------------- GEMM: C[M][N] = A[M][K](bf16) @ BT[N][K](bf16)^T + bias ----------------
// BM=256, BN=128, BK=32, 256 threads (4 waves: 2M x 2N), per-wave output 128x64.
// 3-buffer LDS pipeline (24KB/buf = 72KB -> 2 blocks/CU), counted vmcnt(6), raw s_barrier.
// Swizzle for 64B rows: byte ^= ((row&3)<<4) via pre-swizzled global source (linear LDS dest).
// OUT_BF16 path additionally scales columns [0,1024) by QK_SCALE (Q pre-scaling).
template<bool OUT_BF16>
__global__ __launch_bounds__(256, 2) void k_gemm_bt(const unsigned short* __restrict__ A,
                                                    const unsigned short* __restrict__ BT,
                                                    const float* __restrict__ bias,
                                                    unsigned short* __restrict__ outb,
                                                    float* __restrict__ outf,
                                                    int M, int N, int K) {
    __shared__ __align__(16) char arena[73728];
    int tid = threadIdx.x;
    int w = tid >> 6, lane = tid & 63;
    int wrow = w >> 1, wcol = w & 1;
    int m0 = blockIdx.y * 256, n0 = blockIdx.x * 128;
    int lr = lane & 15, lg = lane >> 4;

    f32x4 acc[8][4] = {};

    // --- staging source pointers (pre-swizzled global col; linear LDS dest) ---
    // A tile 256x32 bf16 = 16KB -> 4 loads/thread; B tile 128x32 = 8KB -> 2 loads.
    int grow = tid >> 2;                                    // 0..63
    int scb = ((tid & 3) << 4) ^ (((tid >> 2) & 3) << 4);   // swizzled col byte
    const char* sA[4];
    const char* sB[2];
#pragma unroll
    for (int rr = 0; rr < 4; ++rr)
        sA[rr] = (const char*)A + (size_t)(m0 + grow + rr * 64) * K * 2 + scb;
#pragma unroll
    for (int rr = 0; rr < 2; ++rr)
        sB[rr] = (const char*)BT + (size_t)(n0 + grow + rr * 64) * K * 2 + scb;

    // --- ds_read fragment bases (tile-invariant; +OFS at use) ---
    int inner = (lg * 16) ^ ((lr & 3) << 4);
    int aoff = wrow * 8192 + lr * 64 + inner;           // A frag: +i*1024
    int boff = 16384 + wcol * 4096 + lr * 64 + inner;   // B frag: +j*1024

#define GSTAGE(OFS)                                                                                 \
    {                                                                                               \
        _Pragma("unroll")                                                                           \
        for (int rr = 0; rr < 4; ++rr) {                                                            \
            __builtin_amdgcn_global_load_lds((const AS1 void*)sA[rr],                               \
                (AS3 void*)(arena + (OFS) + tid * 16 + rr * 4096), 16, 0, 0);                       \
            sA[rr] += 64;                                                                           \
        }                                                                                           \
        _Pragma("unroll")                                                                           \
        for (int rr = 0; rr < 2; ++rr) {                                                            \
            __builtin_amdgcn_global_load_lds((const AS1 void*)sB[rr],                               \
                (AS3 void*)(arena + (OFS) + 16384 + tid * 16 + rr * 4096), 16, 0, 0);               \
            sB[rr] += 64;                                                                           \
        }                                                                                           \
    }

#define GCOMPUTE(OFS)                                                                               \
    {                                                                                               \
        short8 af[8], bf[4];                                                                        \
        _Pragma("unroll")                                                                           \
        for (int i = 0; i < 8; ++i)                                                                 \
            af[i] = *(const short8*)(arena + (OFS) + aoff + i * 1024);                              \
        _Pragma("unroll")                                                                           \
        for (int j = 0; j < 4; ++j)                                                                 \
            bf[j] = *(const short8*)(arena + (OFS) + boff + j * 1024);                              \
        __builtin_amdgcn_s_setprio(1);                                                              \
        _Pragma("unroll")                                                                           \
        for (int i = 0; i < 8; ++i)                                                                 \
            _Pragma("unroll")                                                                       \
            for (int j = 0; j < 4; ++j)                                                             \
                acc[i][j] = __builtin_amdgcn_mfma_f32_16x16x32_bf16(af[i], bf[j], acc[i][j], 0, 0, 0); \
        __builtin_amdgcn_s_setprio(0);                                                              \
    }

    int NT = K >> 5;   // K / 32
    int ofs0 = 0, ofs1 = 24576, ofs2 = 49152;

    GSTAGE(ofs0);
    GSTAGE(ofs1);
    asm volatile("s_waitcnt vmcnt(6)" ::: "memory");   // tile 0 complete (tile 1 in flight)
    __builtin_amdgcn_s_barrier();
    __builtin_amdgcn_sched_barrier(0);

    for (int t = 0; t < NT; ++t) {
        bool pf = (t + 2 < NT);
        if (pf) GSTAGE(ofs2);
        GCOMPUTE(ofs0);
        if (pf) { asm volatile("s_waitcnt vmcnt(6)" ::: "memory"); }
        else    { asm volatile("s_waitcnt vmcnt(0)" ::: "memory"); }
        __builtin_amdgcn_s_barrier();
        __builtin_amdgcn_sched_barrier(0);
        int tmp = ofs0; ofs0 = ofs1; ofs1 = ofs2; ofs2 = tmp;
    }
#undef GSTAGE
#undef GCOMPUTE

    // ---- epilogue: per-wave 128x64 at (wrow*128, wcol*64) ----
#pragma unroll
    for (int i = 0; i < 8; ++i) {
        int row = m0 + wrow * 128 + i * 16 + lg * 4;
#pragma unroll
        for (int j = 0; j < 4; ++j) {
            int col = n0 + wcol * 64 + j * 16 + lr;
            float bv = bias[col];
#pragma unroll
            for (int r = 0; r < 4; ++r) {
                float v = acc[i][j][r] + bv;
                if (OUT_BF16) {
                    if (col < C_) v *= QK_SCALE;   // pre-scale Q columns
                    outb[(size_t)(row + r) * N + col] = f2bf(v);
                } else {
                    outf[(size_t)(row + r) * N + col] = v;
                }
            }
        }
    }
}

// ---------------- causal flash attention (swapped QK^T, no-max softmax) ----------------
// LDS arena layout (bytes):
//   [0,8192)      K buf0      [8192,16384)   K buf1
//   [16384,24576) V buf0      [24576,32768)  V buf1
//   [32768,40960) P per-wave (w*2048), conflict-free half-parity swizzle
__global__ __launch_bounds__(256, 4) void k_attn(const unsigned short* __restrict__ qkv,
                                                 const unsigned short* __restrict__ vt,
                                                 unsigned short* __restrict__ y) {
    __shared__ __align__(16) char arena[40960];
    int tid = threadIdx.x;
    int w = tid >> 6, lane = tid & 63;
    int lr = lane & 15, lg = lane >> 4;

    // bijective XCD-chunk swizzle (1024 % 8 == 0)
    int bid = blockIdx.x;
    int bid2 = (bid & 7) * 128 + (bid >> 3);
    int bh = bid2 >> 4, pair = bid2 & 15;
    int b = bh >> 4, h = bh & 15;

    const unsigned short* kbase = qkv + (size_t)(b * T_) * C3_ + C_ + h * D_;
    const unsigned short* vtb = vt + (size_t)bh * D_ * T_;

    // --- precomputed LDS addresses (tile-invariant) ---
    int sw_ = (lr & 7) << 4;
    int RB0 = lr * 128 + ((lg * 16) ^ sw_);   // K/V frag base (imm: arrayoff + buf + j*2048)
    int RB1 = RB0 ^ 64;
    int jl = (lr >> 1) & 3;
    int pbase = 32768 + w * 2048 + lr * 128
              + ((((lg >> 1) ^ (lr & 1)) << 4) | (((lg & 1) ^ (lr >> 3)) << 3));
    int pwa[4];
#pragma unroll
    for (int j = 0; j < 4; ++j) pwa[j] = pbase + ((j ^ jl) << 5);
    // P A-frag read addresses: XOR for the 64-offset (bit 6 lives inside the
    // swizzled column field — ADDITION WOULD CARRY into the row bits), plus
    // half-swap (+8, never carries: bit 3 of prd0 is 0) baked into the address.
    int prd0 = 32768 + w * 2048 + lr * 128 + ((lg ^ (lr & 7)) << 4);
    int prd1 = prd0 ^ 64;
    int hs = lr & 8;
    int prA0a = prd0 + hs,       prA0b = prd0 + (8 ^ hs);
    int prA1a = prd1 + hs,       prA1b = prd1 + (8 ^ hs);

    // --- global stage sources (loop-carried pointers) ---
    int row0 = tid >> 3, row1 = 32 + (tid >> 3);
    int scol0 = ((tid & 7) << 4) ^ ((row0 & 7) << 4);
    int scol1 = ((tid & 7) << 4) ^ ((row1 & 7) << 4);

    const char *sK0, *sK1, *sV0, *sV1;

#define ASTAGE(LDSOFF)                                                                                  \
    {                                                                                                   \
        __builtin_amdgcn_global_load_lds((const AS1 void*)sK0, (AS3 void*)(arena + (LDSOFF) + w * 1024), 16, 0, 0);          \
        __builtin_amdgcn_global_load_lds((const AS1 void*)sK1, (AS3 void*)(arena + (LDSOFF) + 4096 + w * 1024), 16, 0, 0);   \
        __builtin_amdgcn_global_load_lds((const AS1 void*)sV0, (AS3 void*)(arena + 16384 + (LDSOFF) + w * 1024), 16, 0, 0);  \
        __builtin_amdgcn_global_load_lds((const AS1 void*)sV1, (AS3 void*)(arena + 16384 + (LDSOFF) + 4096 + w * 1024), 16, 0, 0); \
        sK0 += 64 * C3_ * 2; sK1 += 64 * C3_ * 2; sV0 += 128; sV1 += 128;                               \
    }

#define ACOMPUTE(LDSOFF, KT)                                                                            \
    {                                                                                                   \
        f32x4 s[4];                                                                                     \
        __builtin_amdgcn_s_setprio(1);                                                                  \
        _Pragma("unroll")                                                                               \
        for (int j = 0; j < 4; ++j) {                                                                   \
            short8 kf0 = *(const short8*)(arena + RB0 + (LDSOFF) + j * 2048);                           \
            short8 kf1 = *(const short8*)(arena + RB1 + (LDSOFF) + j * 2048);                           \
            f32x4 z = {};                                                                               \
            z = __builtin_amdgcn_mfma_f32_16x16x32_bf16(kf0, qf0, z, 0, 0, 0);                          \
            s[j] = __builtin_amdgcn_mfma_f32_16x16x32_bf16(kf1, qf1, z, 0, 0, 0);                       \
        }                                                                                               \
        __builtin_amdgcn_s_setprio(0);                                                                  \
        if ((KT) == ntiles - 1) {                                                                       \
            int kb = (KT) * 64 + lg * 4 - qv;                                                           \
            _Pragma("unroll")                                                                           \
            for (int j = 0; j < 4; ++j)                                                                 \
                _Pragma("unroll")                                                                       \
                for (int r = 0; r < 4; ++r)                                                             \
                    if (kb + j * 16 + r > 0) s[j][r] = -INFINITY;                                       \
        }                                                                                               \
        _Pragma("unroll")                                                                               \
        for (int j = 0; j < 4; ++j)                                                                     \
            _Pragma("unroll")                                                                           \
            for (int r = 0; r < 4; ++r) {                                                               \
                float pv = __builtin_amdgcn_exp2f(s[j][r]);                                             \
                s[j][r] = pv;                                                                           \
                ls += pv;                                                                               \
            }                                                                                           \
        _Pragma("unroll")                                                                               \
        for (int j = 0; j < 4; ++j) {                                                                   \
            uint2v W;                                                                                   \
            W[0] = pk_bf16(s[j][0], s[j][1]);                                                           \
            W[1] = pk_bf16(s[j][2], s[j][3]);                                                           \
            *(uint2v*)(arena + pwa[j]) = W;                                                             \
        }                                                                                               \
        short4v l0 = *(const short4v*)(arena + prA0a);                                                  \
        short4v h0 = *(const short4v*)(arena + prA0b);                                                  \
        short4v l1 = *(const short4v*)(arena + prA1a);                                                  \
        short4v h1 = *(const short4v*)(arena + prA1b);                                                  \
        short8 pa0 = __builtin_shufflevector(l0, h0, 0, 1, 2, 3, 4, 5, 6, 7);                           \
        short8 pa1 = __builtin_shufflevector(l1, h1, 0, 1, 2, 3, 4, 5, 6, 7);                           \
        __builtin_amdgcn_s_setprio(1);                                                                  \
        _Pragma("unroll")                                                                               \
        for (int dt = 0; dt < 4; ++dt) {                                                                \
            short8 vf0 = *(const short8*)(arena + RB0 + 16384 + (LDSOFF) + dt * 2048);                  \
            short8 vf1 = *(const short8*)(arena + RB1 + 16384 + (LDSOFF) + dt * 2048);                  \
            o[dt] = __builtin_amdgcn_mfma_f32_16x16x32_bf16(pa0, vf0, o[dt], 0, 0, 0);                  \
            o[dt] = __builtin_amdgcn_mfma_f32_16x16x32_bf16(pa1, vf1, o[dt], 0, 0, 0);                  \
        }                                                                                               \
        __builtin_amdgcn_s_setprio(0);                                                                  \
    }

#pragma unroll 1
    for (int half = 0; half < 2; ++half) {
        int qt = half ? (31 - pair) : pair;
        int q0 = qt * 64;
        int ntiles = qt + 1;

        const unsigned short* qrow = qkv + (size_t)(b * T_ + q0 + w * 16 + lr) * C3_ + h * D_;
        short8 qf0 = *(const short8*)(qrow + lg * 8);
        short8 qf1 = *(const short8*)(qrow + 32 + lg * 8);

        f32x4 o[4] = {};
        float ls = 0.f;    // in-lane partial of unnormalized row-sum (q = q0 + w*16 + lr)
        int qv = q0 + w * 16 + lr;

        sK0 = (const char*)(kbase + (size_t)row0 * C3_) + scol0;
        sK1 = (const char*)(kbase + (size_t)row1 * C3_) + scol1;
        sV0 = (const char*)(vtb + (size_t)row0 * T_) + scol0;
        sV1 = (const char*)(vtb + (size_t)row1 * T_) + scol1;

        ASTAGE(0);
        asm volatile("s_waitcnt vmcnt(0)" ::: "memory");
        __syncthreads();

#pragma unroll 1
        for (int kt = 0; kt < ntiles; kt += 2) {
            if (kt + 1 < ntiles) ASTAGE(8192);
            ACOMPUTE(0, kt);
            asm volatile("s_waitcnt vmcnt(0)" ::: "memory");
            __syncthreads();
            if (kt + 1 < ntiles) {
                if (kt + 2 < ntiles) ASTAGE(0);
                ACOMPUTE(8192, kt + 1);
                asm volatile("s_waitcnt vmcnt(0)" ::: "memory");
                __syncthreads();
            }
        }

        // ---- combine lg-partials of ls, normalize + store ----
        ls += __shfl_xor(ls, 16);
        ls += __shfl_xor(ls, 32);
#pragma unroll
        for (int r = 0; r < 4; ++r) {
            float lst = __shfl(ls, lg * 4 + r, 64);
            float inv = 1.0f / lst;
            int q = q0 + w * 16 + lg * 4 + r;
            unsigned short* yrow = y + (size_t)(b * T_ + q) * C_ + h * D_;
#pragma unroll
            for (int dt = 0; dt < 4; ++dt)
                yrow[dt * 16 + lr] = f2bf(o[dt][r] * inv);
        }
    }
#undef ASTAGE
#undef ACOMPUTE
}

extern "C" void kernel_launch(void* const* d_in, const int* in_sizes, int n_in,
                              void* d_out, int out_size, void* d_ws, size_t ws_size,
                              hipStream_t stream) {
    const float* x  = (const float*)d_in[0];
    const float* Wa = (const float*)d_in[1];
    const float* ba = (const float*)d_in[2];
    const float* Wp = (const float*)d_in[3];
    const float* bp = (const float*)d_in[4];
    float* out = (float*)d_out;

    char* ws = (char*)d_ws;
    unsigned short* xb  = (unsigned short*)(ws);                       // 16 MB
    unsigned short* wat = (unsigned short*)(ws + 16777216);            // 6 MB
    unsigned short* wpt = (unsigned short*)(ws + 23068672);            // 2 MB
    unsigned short* qkv = (unsigned short*)(ws + 25165824);            // 48 MB
    unsigned short* vt  = (unsigned short*)(ws + 75497472);            // 16 MB
    unsigned short* y   = xb;  // xb dead after GEMM1; reuse for attention output

    // x -> bf16
    k_cvt_bf16<<<8192, 256, 0, stream>>>(x, xb, (B_ * T_ * C_) / 4);
    // weights -> bf16 transposed
    k_wtrans<<<dim3(C3_ / 32, C_ / 32), dim3(32, 8), 0, stream>>>(Wa, wat, C_, C3_);
    k_wtrans<<<dim3(C_ / 32, C_ / 32), dim3(32, 8), 0, stream>>>(Wp, wpt, C_, C_);
    // qkv = x @ W_attn + b_attn   (bf16 out, Q pre-scaled)
    k_gemm_bt<true><<<dim3(C3_ / 128, (B_ * T_) / 256), 256, 0, stream>>>(
        xb, wat, ba, qkv, nullptr, B_ * T_, C3_, C_);
    // v -> vt[bh][d][t]
    k_prep_vt<<<dim3(T_ / 64, B_ * H_), 256, 0, stream>>>(qkv, vt);
    // attention
    k_attn<<<1024, 256, 0, stream>>>(qkv, vt, y);
    // out = y @ W_proj + b_proj   (fp32 out)
    k_gemm_bt<false><<<dim3(C_ / 128, (B_ * T_) / 256), 256, 0, stream>>>(
        y, wpt, bp, nullptr, out, B_ * T_, C_, C_);
}

// Round 10
// 159.894 us; speedup vs baseline: 3.7780x; 1.0382x over previous
//
#include <hip/hip_runtime.h>
#include <stdint.h>

typedef __attribute__((ext_vector_type(8))) short short8;
typedef __attribute__((ext_vector_type(4))) short short4v;
typedef __attribute__((ext_vector_type(4))) float f32x4;
typedef __attribute__((ext_vector_type(2))) unsigned int uint2v;

#define B_ 4
#define T_ 2048
#define C_ 1024
#define H_ 16
#define D_ 64
#define C3_ 3072

#define AS1 __attribute__((address_space(1)))
#define AS3 __attribute__((address_space(3)))

#define QK_SCALE 0.18033688f   /* 1/sqrt(64) * log2(e), folded into Q at GEMM1 epilogue */

__device__ __forceinline__ unsigned short f2bf(float f) {
    union { float f; uint32_t u; } v; v.f = f;
    uint32_t r = v.u + 0x7FFFu + ((v.u >> 16) & 1u);
    return (unsigned short)(r >> 16);
}

__device__ __forceinline__ uint32_t pk_bf16(float lo, float hi) {
    uint32_t r;
    asm("v_cvt_pk_bf16_f32 %0, %1, %2" : "=v"(r) : "v"(lo), "v"(hi));
    return r;
}

// ---------------- fp32 -> bf16 elementwise ----------------
__global__ void k_cvt_bf16(const float* __restrict__ in, unsigned short* __restrict__ out, int n4) {
    int i = blockIdx.x * blockDim.x + threadIdx.x;
    if (i >= n4) return;
    float4 v = ((const float4*)in)[i];
    unsigned short o0 = f2bf(v.x), o1 = f2bf(v.y), o2 = f2bf(v.z), o3 = f2bf(v.w);
    unsigned long long packed = (unsigned long long)o0 | ((unsigned long long)o1 << 16)
        | ((unsigned long long)o2 << 32) | ((unsigned long long)o3 << 48);
    *(unsigned long long*)(out + (size_t)i * 4) = packed;
}

// ---------------- W[K][N] fp32 -> WT[N][K] bf16 ----------------
__global__ void k_wtrans(const float* __restrict__ W, unsigned short* __restrict__ WT, int K, int N) {
    __shared__ float t[32][33];
    int n0 = blockIdx.x * 32, k0 = blockIdx.y * 32;
    int tx = threadIdx.x, ty = threadIdx.y; // (32,8)
#pragma unroll
    for (int i = 0; i < 4; ++i)
        t[ty + i * 8][tx] = W[(size_t)(k0 + ty + i * 8) * N + n0 + tx];
    __syncthreads();
#pragma unroll
    for (int i = 0; i < 4; ++i)
        WT[(size_t)(n0 + ty + i * 8) * K + k0 + tx] = f2bf(t[tx][ty + i * 8]);
}

// ---------------- extract V head-major transposed: vt[bh][d][t] ----------------
__global__ void k_prep_vt(const unsigned short* __restrict__ qkv, unsigned short* __restrict__ vt) {
    int bh = blockIdx.y; int b = bh >> 4, h = bh & 15;
    int t0 = blockIdx.x * 64;
    __shared__ unsigned short tile[64][72];
    int tid = threadIdx.x;
    int r = tid >> 3;          // 0..31
    int c = (tid & 7) * 8;     // 0..56
#pragma unroll
    for (int rr = 0; rr < 64; rr += 32) {
        const unsigned short* src = qkv + (size_t)(b * T_ + t0 + r + rr) * C3_ + 2 * C_ + h * D_ + c;
        short8 v = *(const short8*)src;
#pragma unroll
        for (int j = 0; j < 8; ++j) tile[r + rr][c + j] = (unsigned short)v[j];
    }
    __syncthreads();
#pragma unroll
    for (int rr = 0; rr < 64; rr += 32) {
        int d = r + rr;
        short8 sv;
#pragma unroll
        for (int j = 0; j < 8; ++j) sv[j] = (short)tile[c + j][d];
        *(short8*)(vt + (size_t)bh * D_ * T_ + (size_t)d * T_ + t0 + c) = sv;
    }
}

// ---------------- GEMM: C[M][N] = A[M][K](bf16) @ BT[N][K](bf16)^T + bias ----------------
// BM=256, BN=128, BK=32, 256 threads (4 waves: 2M x 2N), per-wave output 128x64.
// 3-buffer LDS pipeline (24KB/buf = 72KB -> 2 blocks/CU), counted vmcnt(6), raw s_barrier.
// Swizzle for 64B rows: slot ^= ((row>>1)&3)  [quad = (4*lr + swz) mod 8 -> 2 lanes/quad, free]
// applied via pre-swizzled global source (linear LDS dest).
// XCD-chunked block swizzle: each XCD gets a contiguous row-major chunk of the grid.
// OUT_BF16 path additionally scales columns [0,1024) by QK_SCALE (Q pre-scaling).
template<bool OUT_BF16>
__global__ __launch_bounds__(256, 2) void k_gemm_bt(const unsigned short* __restrict__ A,
                                                    const unsigned short* __restrict__ BT,
                                                    const float* __restrict__ bias,
                                                    unsigned short* __restrict__ outb,
                                                    float* __restrict__ outf,
                                                    int M, int N, int K) {
    __shared__ __align__(16) char arena[73728];
    int tid = threadIdx.x;
    int w = tid >> 6, lane = tid & 63;
    int wrow = w >> 1, wcol = w & 1;

    // --- bijective XCD-chunked grid swizzle (grid size always % 8 == 0 here) ---
    int lin = blockIdx.y * gridDim.x + blockIdx.x;
    int nwg8 = (gridDim.x * gridDim.y) >> 3;
    int newlin = (lin & 7) * nwg8 + (lin >> 3);
    int bx = newlin % gridDim.x;
    int by = newlin / gridDim.x;
    int m0 = by * 256, n0 = bx * 128;

    int lr = lane & 15, lg = lane >> 4;

    f32x4 acc[8][4] = {};

    // --- staging source pointers (pre-swizzled global col; linear LDS dest) ---
    // A tile 256x32 bf16 = 16KB -> 4 loads/thread; B tile 128x32 = 8KB -> 2 loads.
    int grow = tid >> 2;                                    // 0..63
    int scb = ((tid & 3) << 4) ^ (((tid >> 3) & 3) << 4);   // swizzled col byte: slot ^ ((row>>1)&3)
    const char* sA[4];
    const char* sB[2];
#pragma unroll
    for (int rr = 0; rr < 4; ++rr)
        sA[rr] = (const char*)A + (size_t)(m0 + grow + rr * 64) * K * 2 + scb;
#pragma unroll
    for (int rr = 0; rr < 2; ++rr)
        sB[rr] = (const char*)BT + (size_t)(n0 + grow + rr * 64) * K * 2 + scb;

    // --- ds_read fragment bases (tile-invariant; +OFS at use) ---
    int inner = (lg * 16) ^ (((lr >> 1) & 3) << 4);
    int aoff = wrow * 8192 + lr * 64 + inner;           // A frag: +i*1024
    int boff = 16384 + wcol * 4096 + lr * 64 + inner;   // B frag: +j*1024

#define GSTAGE(OFS)                                                                                 \
    {                                                                                               \
        _Pragma("unroll")                                                                           \
        for (int rr = 0; rr < 4; ++rr) {                                                            \
            __builtin_amdgcn_global_load_lds((const AS1 void*)sA[rr],                               \
                (AS3 void*)(arena + (OFS) + tid * 16 + rr * 4096), 16, 0, 0);                       \
            sA[rr] += 64;                                                                           \
        }                                                                                           \
        _Pragma("unroll")                                                                           \
        for (int rr = 0; rr < 2; ++rr) {                                                            \
            __builtin_amdgcn_global_load_lds((const AS1 void*)sB[rr],                               \
                (AS3 void*)(arena + (OFS) + 16384 + tid * 16 + rr * 4096), 16, 0, 0);               \
            sB[rr] += 64;                                                                           \
        }                                                                                           \
    }

#define GCOMPUTE(OFS)                                                                               \
    {                                                                                               \
        short8 af[8], bf[4];                                                                        \
        _Pragma("unroll")                                                                           \
        for (int i = 0; i < 8; ++i)                                                                 \
            af[i] = *(const short8*)(arena + (OFS) + aoff + i * 1024);                              \
        _Pragma("unroll")                                                                           \
        for (int j = 0; j < 4; ++j)                                                                 \
            bf[j] = *(const short8*)(arena + (OFS) + boff + j * 1024);                              \
        __builtin_amdgcn_s_setprio(1);                                                              \
        _Pragma("unroll")                                                                           \
        for (int i = 0; i < 8; ++i)                                                                 \
            _Pragma("unroll")                                                                       \
            for (int j = 0; j < 4; ++j)                                                             \
                acc[i][j] = __builtin_amdgcn_mfma_f32_16x16x32_bf16(af[i], bf[j], acc[i][j], 0, 0, 0); \
        __builtin_amdgcn_s_setprio(0);                                                              \
    }

    int NT = K >> 5;   // K / 32
    int ofs0 = 0, ofs1 = 24576, ofs2 = 49152;

    GSTAGE(ofs0);
    GSTAGE(ofs1);
    asm volatile("s_waitcnt vmcnt(6)" ::: "memory");   // tile 0 complete (tile 1 in flight)
    __builtin_amdgcn_s_barrier();
    __builtin_amdgcn_sched_barrier(0);

    for (int t = 0; t < NT; ++t) {
        bool pf = (t + 2 < NT);
        if (pf) GSTAGE(ofs2);
        GCOMPUTE(ofs0);
        if (pf) { asm volatile("s_waitcnt vmcnt(6)" ::: "memory"); }
        else    { asm volatile("s_waitcnt vmcnt(0)" ::: "memory"); }
        __builtin_amdgcn_s_barrier();
        __builtin_amdgcn_sched_barrier(0);
        int tmp = ofs0; ofs0 = ofs1; ofs1 = ofs2; ofs2 = tmp;
    }
#undef GSTAGE
#undef GCOMPUTE

    // ---- epilogue: per-wave 128x64 at (wrow*128, wcol*64) ----
#pragma unroll
    for (int i = 0; i < 8; ++i) {
        int row = m0 + wrow * 128 + i * 16 + lg * 4;
#pragma unroll
        for (int j = 0; j < 4; ++j) {
            int col = n0 + wcol * 64 + j * 16 + lr;
            float bv = bias[col];
#pragma unroll
            for (int r = 0; r < 4; ++r) {
                float v = acc[i][j][r] + bv;
                if (OUT_BF16) {
                    if (col < C_) v *= QK_SCALE;   // pre-scale Q columns
                    outb[(size_t)(row + r) * N + col] = f2bf(v);
                } else {
                    outf[(size_t)(row + r) * N + col] = v;
                }
            }
        }
    }
}

// ---------------- causal flash attention (swapped QK^T, no-max softmax) ----------------
// LDS arena layout (bytes):
//   [0,8192)      K buf0      [8192,16384)   K buf1
//   [16384,24576) V buf0      [24576,32768)  V buf1
//   [32768,40960) P per-wave (w*2048), conflict-free half-parity swizzle
__global__ __launch_bounds__(256, 4) void k_attn(const unsigned short* __restrict__ qkv,
                                                 const unsigned short* __restrict__ vt,
                                                 unsigned short* __restrict__ y) {
    __shared__ __align__(16) char arena[40960];
    int tid = threadIdx.x;
    int w = tid >> 6, lane = tid & 63;
    int lr = lane & 15, lg = lane >> 4;

    // bijective XCD-chunk swizzle (1024 % 8 == 0)
    int bid = blockIdx.x;
    int bid2 = (bid & 7) * 128 + (bid >> 3);
    int bh = bid2 >> 4, pair = bid2 & 15;
    int b = bh >> 4, h = bh & 15;

    const unsigned short* kbase = qkv + (size_t)(b * T_) * C3_ + C_ + h * D_;
    const unsigned short* vtb = vt + (size_t)bh * D_ * T_;

    // --- precomputed LDS addresses (tile-invariant) ---
    int sw_ = (lr & 7) << 4;
    int RB0 = lr * 128 + ((lg * 16) ^ sw_);   // K/V frag base (imm: arrayoff + buf + j*2048)
    int RB1 = RB0 ^ 64;
    int jl = (lr >> 1) & 3;
    int pbase = 32768 + w * 2048 + lr * 128
              + ((((lg >> 1) ^ (lr & 1)) << 4) | (((lg & 1) ^ (lr >> 3)) << 3));
    int pwa[4];
#pragma unroll
    for (int j = 0; j < 4; ++j) pwa[j] = pbase + ((j ^ jl) << 5);
    // P A-frag read addresses: XOR for the 64-offset (bit 6 lives inside the
    // swizzled column field — ADDITION WOULD CARRY into the row bits), plus
    // half-swap (+8, never carries: bit 3 of prd0 is 0) baked into the address.
    int prd0 = 32768 + w * 2048 + lr * 128 + ((lg ^ (lr & 7)) << 4);
    int prd1 = prd0 ^ 64;
    int hs = lr & 8;
    int prA0a = prd0 + hs,       prA0b = prd0 + (8 ^ hs);
    int prA1a = prd1 + hs,       prA1b = prd1 + (8 ^ hs);

    // --- global stage sources (loop-carried pointers) ---
    int row0 = tid >> 3, row1 = 32 + (tid >> 3);
    int scol0 = ((tid & 7) << 4) ^ ((row0 & 7) << 4);
    int scol1 = ((tid & 7) << 4) ^ ((row1 & 7) << 4);

    const char *sK0, *sK1, *sV0, *sV1;

#define ASTAGE(LDSOFF)                                                                                  \
    {                                                                                                   \
        __builtin_amdgcn_global_load_lds((const AS1 void*)sK0, (AS3 void*)(arena + (LDSOFF) + w * 1024), 16, 0, 0);          \
        __builtin_amdgcn_global_load_lds((const AS1 void*)sK1, (AS3 void*)(arena + (LDSOFF) + 4096 + w * 1024), 16, 0, 0);   \
        __builtin_amdgcn_global_load_lds((const AS1 void*)sV0, (AS3 void*)(arena + 16384 + (LDSOFF) + w * 1024), 16, 0, 0);  \
        __builtin_amdgcn_global_load_lds((const AS1 void*)sV1, (AS3 void*)(arena + 16384 + (LDSOFF) + 4096 + w * 1024), 16, 0, 0); \
        sK0 += 64 * C3_ * 2; sK1 += 64 * C3_ * 2; sV0 += 128; sV1 += 128;                               \
    }

#define ACOMPUTE(LDSOFF, KT)                                                                            \
    {                                                                                                   \
        f32x4 s[4];                                                                                     \
        __builtin_amdgcn_s_setprio(1);                                                                  \
        _Pragma("unroll")                                                                               \
        for (int j = 0; j < 4; ++j) {                                                                   \
            short8 kf0 = *(const short8*)(arena + RB0 + (LDSOFF) + j * 2048);                           \
            short8 kf1 = *(const short8*)(arena + RB1 + (LDSOFF) + j * 2048);                           \
            f32x4 z = {};                                                                               \
            z = __builtin_amdgcn_mfma_f32_16x16x32_bf16(kf0, qf0, z, 0, 0, 0);                          \
            s[j] = __builtin_amdgcn_mfma_f32_16x16x32_bf16(kf1, qf1, z, 0, 0, 0);                       \
        }                                                                                               \
        __builtin_amdgcn_s_setprio(0);                                                                  \
        if ((KT) == ntiles - 1) {                                                                       \
            int kb = (KT) * 64 + lg * 4 - qv;                                                           \
            _Pragma("unroll")                                                                           \
            for (int j = 0; j < 4; ++j)                                                                 \
                _Pragma("unroll")                                                                       \
                for (int r = 0; r < 4; ++r)                                                             \
                    if (kb + j * 16 + r > 0) s[j][r] = -INFINITY;                                       \
        }                                                                                               \
        _Pragma("unroll")                                                                               \
        for (int j = 0; j < 4; ++j)                                                                     \
            _Pragma("unroll")                                                                           \
            for (int r = 0; r < 4; ++r) {                                                               \
                float pv = __builtin_amdgcn_exp2f(s[j][r]);                                             \
                s[j][r] = pv;                                                                           \
                ls += pv;                                                                               \
            }                                                                                           \
        _Pragma("unroll")                                                                               \
        for (int j = 0; j < 4; ++j) {                                                                   \
            uint2v W;                                                                                   \
            W[0] = pk_bf16(s[j][0], s[j][1]);                                                           \
            W[1] = pk_bf16(s[j][2], s[j][3]);                                                           \
            *(uint2v*)(arena + pwa[j]) = W;                                                             \
        }                                                                                               \
        short4v l0 = *(const short4v*)(arena + prA0a);                                                  \
        short4v h0 = *(const short4v*)(arena + prA0b);                                                  \
        short4v l1 = *(const short4v*)(arena + prA1a);                                                  \
        short4v h1 = *(const short4v*)(arena + prA1b);                                                  \
        short8 pa0 = __builtin_shufflevector(l0, h0, 0, 1, 2, 3, 4, 5, 6, 7);                           \
        short8 pa1 = __builtin_shufflevector(l1, h1, 0, 1, 2, 3, 4, 5, 6, 7);                           \
        __builtin_amdgcn_s_setprio(1);                                                                  \
        _Pragma("unroll")                                                                               \
        for (int dt = 0; dt < 4; ++dt) {                                                                \
            short8 vf0 = *(const short8*)(arena + RB0 + 16384 + (LDSOFF) + dt * 2048);                  \
            short8 vf1 = *(const short8*)(arena + RB1 + 16384 + (LDSOFF) + dt * 2048);                  \
            o[dt] = __builtin_amdgcn_mfma_f32_16x16x32_bf16(pa0, vf0, o[dt], 0, 0, 0);                  \
            o[dt] = __builtin_amdgcn_mfma_f32_16x16x32_bf16(pa1, vf1, o[dt], 0, 0, 0);                  \
        }                                                                                               \
        __builtin_amdgcn_s_setprio(0);                                                                  \
    }

#pragma unroll 1
    for (int half = 0; half < 2; ++half) {
        int qt = half ? (31 - pair) : pair;
        int q0 = qt * 64;
        int ntiles = qt + 1;

        const unsigned short* qrow = qkv + (size_t)(b * T_ + q0 + w * 16 + lr) * C3_ + h * D_;
        short8 qf0 = *(const short8*)(qrow + lg * 8);
        short8 qf1 = *(const short8*)(qrow + 32 + lg * 8);

        f32x4 o[4] = {};
        float ls = 0.f;    // in-lane partial of unnormalized row-sum (q = q0 + w*16 + lr)
        int qv = q0 + w * 16 + lr;

        sK0 = (const char*)(kbase + (size_t)row0 * C3_) + scol0;
        sK1 = (const char*)(kbase + (size_t)row1 * C3_) + scol1;
        sV0 = (const char*)(vtb + (size_t)row0 * T_) + scol0;
        sV1 = (const char*)(vtb + (size_t)row1 * T_) + scol1;

        ASTAGE(0);
        asm volatile("s_waitcnt vmcnt(0)" ::: "memory");
        __syncthreads();

#pragma unroll 1
        for (int kt = 0; kt < ntiles; kt += 2) {
            if (kt + 1 < ntiles) ASTAGE(8192);
            ACOMPUTE(0, kt);
            asm volatile("s_waitcnt vmcnt(0)" ::: "memory");
            __syncthreads();
            if (kt + 1 < ntiles) {
                if (kt + 2 < ntiles) ASTAGE(0);
                ACOMPUTE(8192, kt + 1);
                asm volatile("s_waitcnt vmcnt(0)" ::: "memory");
                __syncthreads();
            }
        }

        // ---- combine lg-partials of ls, normalize + store ----
        ls += __shfl_xor(ls, 16);
        ls += __shfl_xor(ls, 32);
#pragma unroll
        for (int r = 0; r < 4; ++r) {
            float lst = __shfl(ls, lg * 4 + r, 64);
            float inv = 1.0f / lst;
            int q = q0 + w * 16 + lg * 4 + r;
            unsigned short* yrow = y + (size_t)(b * T_ + q) * C_ + h * D_;
#pragma unroll
            for (int dt = 0; dt < 4; ++dt)
                yrow[dt * 16 + lr] = f2bf(o[dt][r] * inv);
        }
    }
#undef ASTAGE
#undef ACOMPUTE
}

extern "C" void kernel_launch(void* const* d_in, const int* in_sizes, int n_in,
                              void* d_out, int out_size, void* d_ws, size_t ws_size,
                              hipStream_t stream) {
    const float* x  = (const float*)d_in[0];
    const float* Wa = (const float*)d_in[1];
    const float* ba = (const float*)d_in[2];
    const float* Wp = (const float*)d_in[3];
    const float* bp = (const float*)d_in[4];
    float* out = (float*)d_out;

    char* ws = (char*)d_ws;
    unsigned short* xb  = (unsigned short*)(ws);                       // 16 MB
    unsigned short* wat = (unsigned short*)(ws + 16777216);            // 6 MB
    unsigned short* wpt = (unsigned short*)(ws + 23068672);            // 2 MB
    unsigned short* qkv = (unsigned short*)(ws + 25165824);            // 48 MB
    unsigned short* vt  = (unsigned short*)(ws + 75497472);            // 16 MB
    unsigned short* y   = xb;  // xb dead after GEMM1; reuse for attention output

    // x -> bf16
    k_cvt_bf16<<<8192, 256, 0, stream>>>(x, xb, (B_ * T_ * C_) / 4);
    // weights -> bf16 transposed
    k_wtrans<<<dim3(C3_ / 32, C_ / 32), dim3(32, 8), 0, stream>>>(Wa, wat, C_, C3_);
    k_wtrans<<<dim3(C_ / 32, C_ / 32), dim3(32, 8), 0, stream>>>(Wp, wpt, C_, C_);
    // qkv = x @ W_attn + b_attn   (bf16 out, Q pre-scaled)
    k_gemm_bt<true><<<dim3(C3_ / 128, (B_ * T_) / 256), 256, 0, stream>>>(
        xb, wat, ba, qkv, nullptr, B_ * T_, C3_, C_);
    // v -> vt[bh][d][t]
    k_prep_vt<<<dim3(T_ / 64, B_ * H_), 256, 0, stream>>>(qkv, vt);
    // attention
    k_attn<<<1024, 256, 0, stream>>>(qkv, vt, y);
    // out = y @ W_proj + b_proj   (fp32 out)
    k_gemm_bt<false><<<dim3(C_ / 128, (B_ * T_) / 256), 256, 0, stream>>>(
        y, wpt, bp, nullptr, out, B_ * T_, C_, C_);
}